// Round 4
// baseline (276.706 us; speedup 1.0000x reference)
//
#include <hip/hip_runtime.h>

#define N 8192
#define C 64
#define S 16

static constexpr float BN_INV = 0.9999950000374997f; // 1/sqrt(1+1e-5)
static constexpr float LN_EPS = 1e-5f;

typedef _Float16 f16x8 __attribute__((ext_vector_type(8)));
typedef float f32x4 __attribute__((ext_vector_type(4)));

// ---------------------------------------------------------------------------
// K1: xq/xk/xv = feats @ W{q,k,v} + b  (8192x64 @ 64x64, f32)
// ---------------------------------------------------------------------------
__global__ __launch_bounds__(256) void qkv_kernel(
    const float* __restrict__ feats,
    const float* __restrict__ Wq, const float* __restrict__ bq,
    const float* __restrict__ Wk, const float* __restrict__ bk,
    const float* __restrict__ Wv, const float* __restrict__ bv,
    float* __restrict__ xq, float* __restrict__ xk, float* __restrict__ xv)
{
    __shared__ float sF[32 * 64];
    __shared__ float sW[3 * 64 * 64];
    const int t = threadIdx.x;
    const int row0 = blockIdx.x * 32;
    {
        const float4* src = (const float4*)(feats + row0 * 64);
        float4* dst = (float4*)sF;
        dst[t] = src[t];
        dst[t + 256] = src[t + 256];
        const float4* wq4 = (const float4*)Wq;
        const float4* wk4 = (const float4*)Wk;
        const float4* wv4 = (const float4*)Wv;
        float4* d0 = (float4*)sW;
        float4* d1 = (float4*)(sW + 4096);
        float4* d2 = (float4*)(sW + 8192);
#pragma unroll
        for (int k = 0; k < 4; k++) {
            d0[t + k * 256] = wq4[t + k * 256];
            d1[t + k * 256] = wk4[t + k * 256];
            d2[t + k * 256] = wv4[t + k * 256];
        }
    }
    __syncthreads();
    const int col = t & 63, rg = t >> 6;
    const float* biases[3] = {bq, bk, bv};
    float* outs[3] = {xq, xk, xv};
    for (int m = 0; m < 3; m++) {
        const float* w = sW + m * 4096;
        float bias = biases[m][col];
        float acc[8];
#pragma unroll
        for (int k = 0; k < 8; k++) acc[k] = bias;
        for (int c = 0; c < 64; c++) {
            float wv = w[c * 64 + col];
#pragma unroll
            for (int k = 0; k < 8; k++)
                acc[k] = fmaf(sF[(rg * 8 + k) * 64 + c], wv, acc[k]);
        }
        float* o = outs[m] + row0 * 64;
#pragma unroll
        for (int k = 0; k < 8; k++) o[(rg * 8 + k) * 64 + col] = acc[k];
    }
}

// ---------------------------------------------------------------------------
// K2: exact 16-NN by (d2, idx) ascending. key = (d2<<13)|idx (30 bits).
// One query per 64-lane wave; 16 named regs (no scratch). Double-buffered
// SoA tile: one barrier/tile, next tile's loads overlap the insert chain.
// ---------------------------------------------------------------------------
__device__ __forceinline__ void sort2(unsigned& x, unsigned& y)
{
    unsigned lo = min(x, y);
    unsigned hi = max(x, y);
    x = lo;
    y = hi;
}

__global__ __launch_bounds__(256) void knn_kernel(
    const int4* __restrict__ idx4, int* __restrict__ knn_out)
{
    __shared__ int tx[2][512], ty[2][512], tz[2][512];
    const int t = threadIdx.x;
    const int lane = t & 63;
    const int wv = t >> 6;
    const int q = blockIdx.x * 4 + wv;
    const int4 qc = idx4[q];
    const int qx = qc.y, qy = qc.z, qz = qc.w;
    unsigned a0 = 0xFFFFFFFFu, a1 = 0xFFFFFFFFu, a2 = 0xFFFFFFFFu,
             a3 = 0xFFFFFFFFu, a4 = 0xFFFFFFFFu, a5 = 0xFFFFFFFFu,
             a6 = 0xFFFFFFFFu, a7 = 0xFFFFFFFFu, a8 = 0xFFFFFFFFu,
             a9 = 0xFFFFFFFFu, a10 = 0xFFFFFFFFu, a11 = 0xFFFFFFFFu,
             a12 = 0xFFFFFFFFu, a13 = 0xFFFFFFFFu, a14 = 0xFFFFFFFFu,
             a15 = 0xFFFFFFFFu;

    {
        int4 c0 = idx4[t];
        int4 c1 = idx4[256 + t];
        tx[0][t] = c0.y; ty[0][t] = c0.z; tz[0][t] = c0.w;
        tx[0][t + 256] = c1.y; ty[0][t + 256] = c1.z; tz[0][t + 256] = c1.w;
    }
    __syncthreads();
    for (int tb = 0; tb < 16; ++tb) {
        const int cur = tb & 1, nxt = cur ^ 1;
        int4 n0, n1;
        if (tb < 15) {
            n0 = idx4[(tb + 1) * 512 + t];
            n1 = idx4[(tb + 1) * 512 + 256 + t];
        }
#pragma unroll
        for (int i = 0; i < 8; ++i) {
            int e = i * 64 + lane;
            int dx = tx[cur][e] - qx, dy = ty[cur][e] - qy,
                dz = tz[cur][e] - qz;
            unsigned d2 = (unsigned)(dx * dx + dy * dy + dz * dz);
            unsigned key = (d2 << 13) | (unsigned)(tb * 512 + e);
            a15 = min(a15, key);
            sort2(a14, a15); sort2(a13, a14); sort2(a12, a13);
            sort2(a11, a12); sort2(a10, a11); sort2(a9, a10);
            sort2(a8, a9);   sort2(a7, a8);   sort2(a6, a7);
            sort2(a5, a6);   sort2(a4, a5);   sort2(a3, a4);
            sort2(a2, a3);   sort2(a1, a2);   sort2(a0, a1);
        }
        if (tb < 15) {
            tx[nxt][t] = n0.y; ty[nxt][t] = n0.z; tz[nxt][t] = n0.w;
            tx[nxt][t + 256] = n1.y;
            ty[nxt][t + 256] = n1.z;
            tz[nxt][t + 256] = n1.w;
        }
        __syncthreads();
    }
    for (int r = 0; r < 16; ++r) {
        unsigned m = a0;
        m = min(m, (unsigned)__shfl_xor((int)m, 1, 64));
        m = min(m, (unsigned)__shfl_xor((int)m, 2, 64));
        m = min(m, (unsigned)__shfl_xor((int)m, 4, 64));
        m = min(m, (unsigned)__shfl_xor((int)m, 8, 64));
        m = min(m, (unsigned)__shfl_xor((int)m, 16, 64));
        m = min(m, (unsigned)__shfl_xor((int)m, 32, 64));
        if (lane == r) knn_out[q * 16 + r] = (int)(m & 8191u);
        bool win = (a0 == m);
        a0 = win ? a1 : a0;    a1 = win ? a2 : a1;
        a2 = win ? a3 : a2;    a3 = win ? a4 : a3;
        a4 = win ? a5 : a4;    a5 = win ? a6 : a5;
        a6 = win ? a7 : a6;    a7 = win ? a8 : a7;
        a8 = win ? a9 : a8;    a9 = win ? a10 : a9;
        a10 = win ? a11 : a10; a11 = win ? a12 : a11;
        a12 = win ? a13 : a12; a13 = win ? a14 : a13;
        a14 = win ? a15 : a14; a15 = win ? 0xFFFFFFFFu : a15;
    }
}

// ---------------------------------------------------------------------------
// K3: MFMA vector-attention. 2048 blocks x 256 thr; ONE query per 64-lane
// wave (R3 ran 4 sequential queries/wave at 512 blocks -> Occupancy 0.5%,
// pure latency starvation). 8192 independent waves; loads batched up-front.
// ---------------------------------------------------------------------------
__global__ __launch_bounds__(256, 2) void attn_kernel(
    const int4* __restrict__ idx4, const int* __restrict__ knn,
    const float* __restrict__ xq, const float* __restrict__ xk,
    const float* __restrict__ xv,
    const float* __restrict__ Wp1, const float* __restrict__ pg,
    const float* __restrict__ pb, const float* __restrict__ Wp2,
    const float* __restrict__ bp2,
    const float* __restrict__ wg1, const float* __restrict__ wb1,
    const float* __restrict__ Ww1,
    const float* __restrict__ wg2, const float* __restrict__ wb2,
    const float* __restrict__ Ww2, const float* __restrict__ bw2,
    float* __restrict__ attn)
{
    __shared__ _Float16 sW1t[128 * 72];
    __shared__ _Float16 sW2t[64 * 136];
    __shared__ _Float16 su[4 * 16 * 72];
    __shared__ _Float16 so1[4 * 16 * 136];
    __shared__ float sWp1[48], sPg[16], sPb[16];

    const int t = threadIdx.x;
    const int lane = t & 63;
    const int wv = t >> 6;
    const int col = lane & 15, g = lane >> 4;
    const int q = blockIdx.x * 4 + wv;

    // issue per-query gather chain ASAP (before weight staging)
    const int jA = knn[q * 16 + col];
    const int4 jC = *(const int4*)(knn + q * 16 + g * 4);
    const int jr[4] = {jC.x, jC.y, jC.z, jC.w};
    const int4 pc = idx4[jA];
    const int4 qc = idx4[q];
    float xqv[4], xkv[4][4], xvv[4][4];
#pragma unroll
    for (int f = 0; f < 4; f++) xqv[f] = xq[q * 64 + f * 16 + col];
#pragma unroll
    for (int r = 0; r < 4; r++)
#pragma unroll
        for (int f = 0; f < 4; f++) {
            xkv[r][f] = xk[jr[r] * 64 + f * 16 + col];
            xvv[r][f] = xv[jr[r] * 64 + f * 16 + col];
        }

    // stage transposed f16 weights
    for (int e = t; e < 8192; e += 256) {
        int c = e >> 7, o = e & 127;
        sW1t[o * 72 + c] = (_Float16)Ww1[e];
    }
    for (int e = t; e < 8192; e += 256) {
        int n = e >> 6, m = e & 63;
        sW2t[m * 136 + n] = (_Float16)Ww2[e];
    }
    if (t < 48) sWp1[t] = Wp1[t];
    if (t < 16) { sPg[t] = pg[t] * BN_INV; sPb[t] = pb[t]; }

    float g1c[4], b1c[4], bp2c[4], bw2c[4], g2c[8], b2c[8];
#pragma unroll
    for (int f = 0; f < 4; f++) {
        int c = f * 16 + col;
        g1c[f] = wg1[c] * BN_INV; b1c[f] = wb1[c];
        bp2c[f] = bp2[c]; bw2c[f] = bw2[c];
    }
#pragma unroll
    for (int f = 0; f < 8; f++) {
        int o = f * 16 + col;
        g2c[f] = wg2[o] * BN_INV; b2c[f] = wb2[o];
    }
    f16x8 bP[4];
#pragma unroll
    for (int f = 0; f < 4; f++) {
#pragma unroll
        for (int j = 0; j < 8; j++) {
            int h = g * 8 + j;
            bP[f][j] = (g < 2) ? (_Float16)Wp2[h * 64 + f * 16 + col]
                               : (_Float16)0.f;
        }
    }
    __syncthreads();

    _Float16* su_w = su + wv * (16 * 72);
    _Float16* so1_w = so1 + wv * (16 * 136);

    // ---- p_r via MFMA: A = ph (row s = col), B = Wp2 ----
    const float px = (float)(pc.y - qc.y);
    const float py = (float)(pc.z - qc.z);
    const float pz = (float)(pc.w - qc.w);
    f16x8 aph;
#pragma unroll
    for (int j = 0; j < 8; j++) {
        int h = g * 8 + j;
        float v = 0.f;
        if (g < 2) {
            v = px * sWp1[h] + py * sWp1[16 + h] + pz * sWp1[32 + h];
            v = fmaxf(v * sPg[h] + sPb[h], 0.f);
        }
        aph[j] = (_Float16)v;
    }
    f32x4 pr[4];
#pragma unroll
    for (int f = 0; f < 4; f++) {
        f32x4 cini;
#pragma unroll
        for (int r = 0; r < 4; r++) cini[r] = bp2c[f];
        pr[f] = __builtin_amdgcn_mfma_f32_16x16x32_f16(aph, bP[f], cini,
                                                       0, 0, 0);
    }
    // ---- u = relu(bn1(xk - xq + pr)) -> LDS(f16); v = xv + pr (regs) ----
    f32x4 vvr[4];
#pragma unroll
    for (int r = 0; r < 4; r++) {
#pragma unroll
        for (int f = 0; f < 4; f++) {
            float w0 = xkv[r][f] - xqv[f] + pr[f][r];
            float uu = fmaxf(w0 * g1c[f] + b1c[f], 0.f);
            su_w[(g * 4 + r) * 72 + f * 16 + col] = (_Float16)uu;
            vvr[f][r] = xvv[r][f] + pr[f][r];
        }
    }
    // ---- GEMM1: o1 = relu(bn2(u @ W1)) ----
    f16x8 au[2];
#pragma unroll
    for (int kc = 0; kc < 2; kc++)
        au[kc] = *(const f16x8*)&su_w[col * 72 + kc * 32 + g * 8];
    f32x4 acc1[8];
#pragma unroll
    for (int f = 0; f < 8; f++)
#pragma unroll
        for (int r = 0; r < 4; r++) acc1[f][r] = 0.f;
#pragma unroll
    for (int kc = 0; kc < 2; kc++) {
#pragma unroll
        for (int f = 0; f < 8; f++) {
            f16x8 bw = *(const f16x8*)
                &sW1t[(f * 16 + col) * 72 + kc * 32 + g * 8];
            acc1[f] = __builtin_amdgcn_mfma_f32_16x16x32_f16(au[kc], bw,
                                                             acc1[f], 0, 0, 0);
        }
    }
#pragma unroll
    for (int f = 0; f < 8; f++)
#pragma unroll
        for (int r = 0; r < 4; r++) {
            float o1 = fmaxf(acc1[f][r] * g2c[f] + b2c[f], 0.f);
            so1_w[(g * 4 + r) * 136 + f * 16 + col] = (_Float16)o1;
        }
    // ---- GEMM2: logits = o1 @ W2 + bw2 ----
    f16x8 ao[4];
#pragma unroll
    for (int kc = 0; kc < 4; kc++)
        ao[kc] = *(const f16x8*)&so1_w[col * 136 + kc * 32 + g * 8];
    f32x4 accL[4];
#pragma unroll
    for (int f = 0; f < 4; f++)
#pragma unroll
        for (int r = 0; r < 4; r++) accL[f][r] = bw2c[f];
#pragma unroll
    for (int kc = 0; kc < 4; kc++) {
#pragma unroll
        for (int f = 0; f < 4; f++) {
            f16x8 bw = *(const f16x8*)
                &sW2t[(f * 16 + col) * 136 + kc * 32 + g * 8];
            accL[f] = __builtin_amdgcn_mfma_f32_16x16x32_f16(ao[kc], bw,
                                                             accL[f], 0, 0, 0);
        }
    }
    // ---- softmax over s + einsum ----
    float outv[4];
#pragma unroll
    for (int f = 0; f < 4; f++) {
        float mx = fmaxf(fmaxf(accL[f][0], accL[f][1]),
                         fmaxf(accL[f][2], accL[f][3]));
        mx = fmaxf(mx, __shfl_xor(mx, 16, 64));
        mx = fmaxf(mx, __shfl_xor(mx, 32, 64));
        float sum = 0.f, part = 0.f;
#pragma unroll
        for (int r = 0; r < 4; r++) {
            float e = __expf(accL[f][r] - mx);
            sum += e;
            part = fmaf(e, vvr[f][r], part);
        }
        sum += __shfl_xor(sum, 16, 64);
        sum += __shfl_xor(sum, 32, 64);
        part += __shfl_xor(part, 16, 64);
        part += __shfl_xor(part, 32, 64);
        outv[f] = part / sum;
    }
    float val = (g == 0) ? outv[0]
              : (g == 1) ? outv[1]
              : (g == 2) ? outv[2] : outv[3];
    attn[q * 64 + lane] = val;
}

// ---------------------------------------------------------------------------
// K4a: h2 = relu(bn(relu(bn([feats,attn] @ Wc1)) @ Wc2))
// ---------------------------------------------------------------------------
__global__ __launch_bounds__(256) void head1_kernel(
    const float* __restrict__ feats, const float* __restrict__ attn,
    const float* __restrict__ Wc1, const float* __restrict__ cg1,
    const float* __restrict__ cb1, const float* __restrict__ Wc2,
    const float* __restrict__ cg2, const float* __restrict__ cb2,
    float* __restrict__ h2out)
{
    __shared__ float sWa[128 * 128];
    __shared__ float sWb[128 * 128];
    __shared__ float sh[16 * 132];
    __shared__ float sh1[16 * 132];
    __shared__ float sga[128], sba[128], sgb[128], sbb[128];
    const int t = threadIdx.x;
    const int row0 = blockIdx.x * 16;
    {
        const float4* a4 = (const float4*)Wc1;
        const float4* b4 = (const float4*)Wc2;
        float4* da = (float4*)sWa;
        float4* db = (float4*)sWb;
#pragma unroll
        for (int k = 0; k < 16; k++) {
            da[t + k * 256] = a4[t + k * 256];
            db[t + k * 256] = b4[t + k * 256];
        }
        if (t < 128) {
            sga[t] = cg1[t] * BN_INV; sba[t] = cb1[t];
            sgb[t] = cg2[t] * BN_INV; sbb[t] = cb2[t];
        }
    }
#pragma unroll
    for (int k = 0; k < 8; k++) {
        int e = t + k * 256;
        int r = e >> 7, c = e & 127;
        float xval = (c < 64) ? feats[(row0 + r) * 64 + c]
                              : attn[(row0 + r) * 64 + (c - 64)];
        sh[r * 132 + c] = xval;
    }
    __syncthreads();
    const int r = t >> 4, ob = (t & 15) * 4;
    {
        float acc[8];
#pragma unroll
        for (int i = 0; i < 8; i++) acc[i] = 0.f;
        const float* hrow = &sh[r * 132];
        for (int c = 0; c < 128; c++) {
            float hv = hrow[c];
#pragma unroll
            for (int i = 0; i < 2; i++) {
                const float* wr = &sWa[c * 128 + ob + 64 * i];
#pragma unroll
                for (int k = 0; k < 4; k++)
                    acc[i * 4 + k] = fmaf(hv, wr[k], acc[i * 4 + k]);
            }
        }
        float* h1row = &sh1[r * 132];
#pragma unroll
        for (int i = 0; i < 2; i++)
#pragma unroll
            for (int k = 0; k < 4; k++) {
                int o = ob + 64 * i + k;
                h1row[o] = fmaxf(acc[i * 4 + k] * sga[o] + sba[o], 0.f);
            }
    }
    __syncthreads();
    {
        float acc[8];
#pragma unroll
        for (int i = 0; i < 8; i++) acc[i] = 0.f;
        const float* hrow = &sh1[r * 132];
        for (int c = 0; c < 128; c++) {
            float hv = hrow[c];
#pragma unroll
            for (int i = 0; i < 2; i++) {
                const float* wr = &sWb[c * 128 + ob + 64 * i];
#pragma unroll
                for (int k = 0; k < 4; k++)
                    acc[i * 4 + k] = fmaf(hv, wr[k], acc[i * 4 + k]);
            }
        }
        float* dst = h2out + (row0 + r) * 128;
#pragma unroll
        for (int i = 0; i < 2; i++)
#pragma unroll
            for (int k = 0; k < 4; k++) {
                int o = ob + 64 * i + k;
                dst[o] = fmaxf(acc[i * 4 + k] * sgb[o] + sbb[o], 0.f);
            }
    }
}

// ---------------------------------------------------------------------------
// K4b: out = LN(h2 @ Wc3 + bc3)
// ---------------------------------------------------------------------------
__global__ __launch_bounds__(256) void head2_kernel(
    const float* __restrict__ h2, const float* __restrict__ Wc3,
    const float* __restrict__ bc3, const float* __restrict__ lng,
    const float* __restrict__ lnb, float* __restrict__ out)
{
    __shared__ float sW[128 * 64];
    __shared__ float sh[16 * 132];
    __shared__ float sg[64], sb[64], sbc[64];
    const int t = threadIdx.x;
    const int row0 = blockIdx.x * 16;
    {
        const float4* w4 = (const float4*)Wc3;
        float4* dw = (float4*)sW;
#pragma unroll
        for (int k = 0; k < 8; k++) dw[t + k * 256] = w4[t + k * 256];
        if (t < 64) { sg[t] = lng[t]; sb[t] = lnb[t]; sbc[t] = bc3[t]; }
        const float4* h4 = (const float4*)(h2 + row0 * 128);
#pragma unroll
        for (int k = 0; k < 2; k++) {
            int e = t + k * 256;
            int r = e >> 5, c4 = (e & 31) * 4;
            *(float4*)&sh[r * 132 + c4] = h4[e];
        }
    }
    __syncthreads();
    const int r = t >> 4, o0 = (t & 15) * 4;
    float acc[4] = {0.f, 0.f, 0.f, 0.f};
    const float* hrow = &sh[r * 132];
    for (int c = 0; c < 128; c++) {
        float hv = hrow[c];
        const float* wr = &sW[c * 64 + o0];
#pragma unroll
        for (int k = 0; k < 4; k++) acc[k] = fmaf(hv, wr[k], acc[k]);
    }
#pragma unroll
    for (int k = 0; k < 4; k++) acc[k] += sbc[o0 + k];
    float s1 = acc[0] + acc[1] + acc[2] + acc[3];
    float s2 = acc[0] * acc[0] + acc[1] * acc[1] + acc[2] * acc[2] +
               acc[3] * acc[3];
#pragma unroll
    for (int d = 1; d < 16; d <<= 1) {
        s1 += __shfl_xor(s1, d, 16);
        s2 += __shfl_xor(s2, d, 16);
    }
    float m = s1 * (1.f / 64.f);
    float var = s2 * (1.f / 64.f) - m * m;
    float inv = 1.f / sqrtf(var + LN_EPS);
    float* dst = out + (row0 + r) * 64;
#pragma unroll
    for (int k = 0; k < 4; k++) {
        int o = o0 + k;
        dst[o] = (acc[k] - m) * inv * sg[o] + sb[o];
    }
}

// ---------------------------------------------------------------------------
extern "C" void kernel_launch(void* const* d_in, const int* in_sizes, int n_in,
                              void* d_out, int out_size, void* d_ws,
                              size_t ws_size, hipStream_t stream)
{
    const int* indices = (const int*)d_in[0];
    const float* feats = (const float*)d_in[1];
    const float* Wq = (const float*)d_in[2];
    const float* bq = (const float*)d_in[3];
    const float* Wk = (const float*)d_in[4];
    const float* bk = (const float*)d_in[5];
    const float* Wv = (const float*)d_in[6];
    const float* bv = (const float*)d_in[7];
    const float* Wp1 = (const float*)d_in[8];
    const float* pg = (const float*)d_in[9];
    const float* pb = (const float*)d_in[10];
    const float* Wp2 = (const float*)d_in[11];
    const float* bp2 = (const float*)d_in[12];
    const float* wg1 = (const float*)d_in[13];
    const float* wb1 = (const float*)d_in[14];
    const float* Ww1 = (const float*)d_in[15];
    const float* wg2 = (const float*)d_in[16];
    const float* wb2 = (const float*)d_in[17];
    const float* Ww2 = (const float*)d_in[18];
    const float* bw2 = (const float*)d_in[19];
    const float* Wc1 = (const float*)d_in[20];
    const float* cg1 = (const float*)d_in[21];
    const float* cb1 = (const float*)d_in[22];
    const float* Wc2 = (const float*)d_in[23];
    const float* cg2 = (const float*)d_in[24];
    const float* cb2 = (const float*)d_in[25];
    const float* Wc3 = (const float*)d_in[26];
    const float* bc3 = (const float*)d_in[27];
    const float* lng = (const float*)d_in[28];
    const float* lnb = (const float*)d_in[29];

    float* out = (float*)d_out;
    float* ws = (float*)d_ws;
    float* xq = ws;
    float* xk = xq + N * C;
    float* xv = xk + N * C;
    float* attn = xv + N * C;
    float* h2 = attn + N * C;             // N*128 floats
    int* knn = (int*)(h2 + N * 2 * C);    // N*16 ints

    qkv_kernel<<<256, 256, 0, stream>>>(feats, Wq, bq, Wk, bk, Wv, bv, xq, xk,
                                        xv);
    knn_kernel<<<2048, 256, 0, stream>>>((const int4*)indices, knn);
    attn_kernel<<<2048, 256, 0, stream>>>((const int4*)indices, knn, xq, xk,
                                          xv, Wp1, pg, pb, Wp2, bp2, wg1, wb1,
                                          Ww1, wg2, wb2, Ww2, bw2, attn);
    head1_kernel<<<512, 256, 0, stream>>>(feats, attn, Wc1, cg1, cb1, Wc2,
                                          cg2, cb2, h2);
    head2_kernel<<<512, 256, 0, stream>>>(h2, Wc3, bc3, lng, lnb, out);
}

// Round 5
// 238.806 us; speedup vs baseline: 1.1587x; 1.1587x over previous
//
#include <hip/hip_runtime.h>

#define N 8192
#define C 64
#define S 16

static constexpr float BN_INV = 0.9999950000374997f; // 1/sqrt(1+1e-5)
static constexpr float LN_EPS = 1e-5f;

typedef _Float16 f16x8 __attribute__((ext_vector_type(8)));
typedef float f32x4 __attribute__((ext_vector_type(4)));

// ---------------------------------------------------------------------------
// K1: xq/xk/xv = feats @ W{q,k,v} + b  (8192x64 @ 64x64, f32)
// ---------------------------------------------------------------------------
__global__ __launch_bounds__(256) void qkv_kernel(
    const float* __restrict__ feats,
    const float* __restrict__ Wq, const float* __restrict__ bq,
    const float* __restrict__ Wk, const float* __restrict__ bk,
    const float* __restrict__ Wv, const float* __restrict__ bv,
    float* __restrict__ xq, float* __restrict__ xk, float* __restrict__ xv)
{
    __shared__ float sF[32 * 64];
    __shared__ float sW[3 * 64 * 64];
    const int t = threadIdx.x;
    const int row0 = blockIdx.x * 32;
    {
        const float4* src = (const float4*)(feats + row0 * 64);
        float4* dst = (float4*)sF;
        dst[t] = src[t];
        dst[t + 256] = src[t + 256];
        const float4* wq4 = (const float4*)Wq;
        const float4* wk4 = (const float4*)Wk;
        const float4* wv4 = (const float4*)Wv;
        float4* d0 = (float4*)sW;
        float4* d1 = (float4*)(sW + 4096);
        float4* d2 = (float4*)(sW + 8192);
#pragma unroll
        for (int k = 0; k < 4; k++) {
            d0[t + k * 256] = wq4[t + k * 256];
            d1[t + k * 256] = wk4[t + k * 256];
            d2[t + k * 256] = wv4[t + k * 256];
        }
    }
    __syncthreads();
    const int col = t & 63, rg = t >> 6;
    const float* biases[3] = {bq, bk, bv};
    float* outs[3] = {xq, xk, xv};
    for (int m = 0; m < 3; m++) {
        const float* w = sW + m * 4096;
        float bias = biases[m][col];
        float acc[8];
#pragma unroll
        for (int k = 0; k < 8; k++) acc[k] = bias;
        for (int c = 0; c < 64; c++) {
            float wv = w[c * 64 + col];
#pragma unroll
            for (int k = 0; k < 8; k++)
                acc[k] = fmaf(sF[(rg * 8 + k) * 64 + c], wv, acc[k]);
        }
        float* o = outs[m] + row0 * 64;
#pragma unroll
        for (int k = 0; k < 8; k++) o[(rg * 8 + k) * 64 + col] = acc[k];
    }
}

// ---------------------------------------------------------------------------
// K2: exact 16-NN by (d2, idx) ascending. key = (d2<<13)|idx (30 bits).
// Top-4 sorted list per lane (7-op insert vs 31-op top-16 chain), width-64
// tournament merge, then EXACT check: a lane can only have dropped a needed
// key if its pre-merge 4th-smallest < global 16th (P~0.7%); such waves redo
// a full 16-deep scan from global. Tile stores (x,y,z,|p|^2) as int4: one
// ds_read_b128/cand and d2 = |q|^2+|p|^2-2*dot.
// ---------------------------------------------------------------------------
__device__ __forceinline__ void sort2(unsigned& x, unsigned& y)
{
    unsigned lo = min(x, y);
    unsigned hi = max(x, y);
    x = lo;
    y = hi;
}

__global__ __launch_bounds__(256) void knn_kernel(
    const int4* __restrict__ idx4, int* __restrict__ knn_out)
{
    __shared__ int4 tile[512];
    const int t = threadIdx.x;
    const int lane = t & 63;
    const int wv = t >> 6;
    const int q = blockIdx.x * 4 + wv;
    const int4 qc = idx4[q];
    const int qx = qc.y, qy = qc.z, qz = qc.w;
    const int qq = qx * qx + qy * qy + qz * qz;
    unsigned a0 = 0xFFFFFFFFu, a1 = 0xFFFFFFFFu, a2 = 0xFFFFFFFFu,
             a3 = 0xFFFFFFFFu;

    for (int tb = 0; tb < 16; ++tb) {
        __syncthreads();
        {
            int4 c0 = idx4[tb * 512 + t];
            int4 c1 = idx4[tb * 512 + 256 + t];
            tile[t] = make_int4(c0.y, c0.z, c0.w,
                                c0.y * c0.y + c0.z * c0.z + c0.w * c0.w);
            tile[t + 256] = make_int4(c1.y, c1.z, c1.w,
                                      c1.y * c1.y + c1.z * c1.z + c1.w * c1.w);
        }
        __syncthreads();
#pragma unroll
        for (int i = 0; i < 8; ++i) {
            int e = i * 64 + lane;
            int4 cd = tile[e];
            int dot = cd.x * qx + cd.y * qy + cd.z * qz;
            unsigned d2 = (unsigned)(qq + cd.w - (dot << 1));
            unsigned key = (d2 << 13) | (unsigned)(tb * 512 + e);
            a3 = min(a3, key);
            sort2(a2, a3);
            sort2(a1, a2);
            sort2(a0, a1);
        }
    }
    const unsigned a3pre = a3;
    unsigned g16 = 0;
    for (int r = 0; r < 16; ++r) {
        unsigned m = a0;
        m = min(m, (unsigned)__shfl_xor((int)m, 1, 64));
        m = min(m, (unsigned)__shfl_xor((int)m, 2, 64));
        m = min(m, (unsigned)__shfl_xor((int)m, 4, 64));
        m = min(m, (unsigned)__shfl_xor((int)m, 8, 64));
        m = min(m, (unsigned)__shfl_xor((int)m, 16, 64));
        m = min(m, (unsigned)__shfl_xor((int)m, 32, 64));
        if (lane == r) knn_out[q * 16 + r] = (int)(m & 8191u);
        bool win = (a0 == m);
        a0 = win ? a1 : a0;
        a1 = win ? a2 : a1;
        a2 = win ? a3 : a2;
        a3 = win ? 0xFFFFFFFFu : a3;
        g16 = m;
    }
    // exactness check: bad iff some lane might have dropped a key < g16
    unsigned long long bad = __ballot(a3pre < g16);
    if (bad) {
        unsigned b0 = 0xFFFFFFFFu, b1 = 0xFFFFFFFFu, b2 = 0xFFFFFFFFu,
                 b3 = 0xFFFFFFFFu, b4 = 0xFFFFFFFFu, b5 = 0xFFFFFFFFu,
                 b6 = 0xFFFFFFFFu, b7 = 0xFFFFFFFFu, b8 = 0xFFFFFFFFu,
                 b9 = 0xFFFFFFFFu, b10 = 0xFFFFFFFFu, b11 = 0xFFFFFFFFu,
                 b12 = 0xFFFFFFFFu, b13 = 0xFFFFFFFFu, b14 = 0xFFFFFFFFu,
                 b15 = 0xFFFFFFFFu;
        for (int i = 0; i < 128; ++i) {
            int j = i * 64 + lane;
            int4 cd = idx4[j];
            int dx = cd.y - qx, dy = cd.z - qy, dz = cd.w - qz;
            unsigned d2 = (unsigned)(dx * dx + dy * dy + dz * dz);
            unsigned key = (d2 << 13) | (unsigned)j;
            b15 = min(b15, key);
            sort2(b14, b15); sort2(b13, b14); sort2(b12, b13);
            sort2(b11, b12); sort2(b10, b11); sort2(b9, b10);
            sort2(b8, b9);   sort2(b7, b8);   sort2(b6, b7);
            sort2(b5, b6);   sort2(b4, b5);   sort2(b3, b4);
            sort2(b2, b3);   sort2(b1, b2);   sort2(b0, b1);
        }
        for (int r = 0; r < 16; ++r) {
            unsigned m = b0;
            m = min(m, (unsigned)__shfl_xor((int)m, 1, 64));
            m = min(m, (unsigned)__shfl_xor((int)m, 2, 64));
            m = min(m, (unsigned)__shfl_xor((int)m, 4, 64));
            m = min(m, (unsigned)__shfl_xor((int)m, 8, 64));
            m = min(m, (unsigned)__shfl_xor((int)m, 16, 64));
            m = min(m, (unsigned)__shfl_xor((int)m, 32, 64));
            if (lane == r) knn_out[q * 16 + r] = (int)(m & 8191u);
            bool win = (b0 == m);
            b0 = win ? b1 : b0;    b1 = win ? b2 : b1;
            b2 = win ? b3 : b2;    b3 = win ? b4 : b3;
            b4 = win ? b5 : b4;    b5 = win ? b6 : b5;
            b6 = win ? b7 : b6;    b7 = win ? b8 : b7;
            b8 = win ? b9 : b8;    b9 = win ? b10 : b9;
            b10 = win ? b11 : b10; b11 = win ? b12 : b11;
            b12 = win ? b13 : b12; b13 = win ? b14 : b13;
            b14 = win ? b15 : b14; b15 = win ? 0xFFFFFFFFu : b15;
        }
    }
}

// ---------------------------------------------------------------------------
// K3: MFMA vector-attention. 1024 blocks x 512 thr; one query per 64-lane
// wave, 8 waves/block. Bigger blocks pack more waves under the same ~71KB
// LDS: 2 blocks/CU -> 16 waves/CU (R4: 8). u and o1 share one per-wave
// scratch (same-wave LDS ordering makes aliasing safe).
// ---------------------------------------------------------------------------
__global__ __launch_bounds__(512, 4) void attn_kernel(
    const int4* __restrict__ idx4, const int* __restrict__ knn,
    const float* __restrict__ xq, const float* __restrict__ xk,
    const float* __restrict__ xv,
    const float* __restrict__ Wp1, const float* __restrict__ pg,
    const float* __restrict__ pb, const float* __restrict__ Wp2,
    const float* __restrict__ bp2,
    const float* __restrict__ wg1, const float* __restrict__ wb1,
    const float* __restrict__ Ww1,
    const float* __restrict__ wg2, const float* __restrict__ wb2,
    const float* __restrict__ Ww2, const float* __restrict__ bw2,
    float* __restrict__ attn)
{
    __shared__ _Float16 sW1t[128 * 72];
    __shared__ _Float16 sW2t[64 * 136];
    __shared__ _Float16 sscr[8][16 * 136]; // per-wave u (stride 72) then o1
    __shared__ float sWp1[48], sPg[16], sPb[16];

    const int t = threadIdx.x;
    const int lane = t & 63;
    const int wv = t >> 6;
    const int col = lane & 15, g = lane >> 4;
    const int q = blockIdx.x * 8 + wv;

    // issue per-query gather chain ASAP (before weight staging)
    const int jA = knn[q * 16 + col];
    const int4 jC = *(const int4*)(knn + q * 16 + g * 4);
    const int jr[4] = {jC.x, jC.y, jC.z, jC.w};
    const int4 pc = idx4[jA];
    const int4 qc = idx4[q];
    float xqv[4], xkv[4][4], xvv[4][4];
#pragma unroll
    for (int f = 0; f < 4; f++) xqv[f] = xq[q * 64 + f * 16 + col];
#pragma unroll
    for (int r = 0; r < 4; r++)
#pragma unroll
        for (int f = 0; f < 4; f++) {
            xkv[r][f] = xk[jr[r] * 64 + f * 16 + col];
            xvv[r][f] = xv[jr[r] * 64 + f * 16 + col];
        }

    // stage transposed f16 weights
    for (int e = t; e < 8192; e += 512) {
        int c = e >> 7, o = e & 127;
        sW1t[o * 72 + c] = (_Float16)Ww1[e];
    }
    for (int e = t; e < 8192; e += 512) {
        int n = e >> 6, m = e & 63;
        sW2t[m * 136 + n] = (_Float16)Ww2[e];
    }
    if (t < 48) sWp1[t] = Wp1[t];
    if (t < 16) { sPg[t] = pg[t] * BN_INV; sPb[t] = pb[t]; }

    float g1c[4], b1c[4], bp2c[4], bw2c[4], g2c[8], b2c[8];
#pragma unroll
    for (int f = 0; f < 4; f++) {
        int c = f * 16 + col;
        g1c[f] = wg1[c] * BN_INV; b1c[f] = wb1[c];
        bp2c[f] = bp2[c]; bw2c[f] = bw2[c];
    }
#pragma unroll
    for (int f = 0; f < 8; f++) {
        int o = f * 16 + col;
        g2c[f] = wg2[o] * BN_INV; b2c[f] = wb2[o];
    }
    f16x8 bP[4];
#pragma unroll
    for (int f = 0; f < 4; f++) {
#pragma unroll
        for (int j = 0; j < 8; j++) {
            int h = g * 8 + j;
            bP[f][j] = (g < 2) ? (_Float16)Wp2[h * 64 + f * 16 + col]
                               : (_Float16)0.f;
        }
    }
    __syncthreads();

    _Float16* scr = sscr[wv];

    // ---- p_r via MFMA: A = ph (row s = col), B = Wp2 ----
    const float px = (float)(pc.y - qc.y);
    const float py = (float)(pc.z - qc.z);
    const float pz = (float)(pc.w - qc.w);
    f16x8 aph;
#pragma unroll
    for (int j = 0; j < 8; j++) {
        int h = g * 8 + j;
        float v = 0.f;
        if (g < 2) {
            v = px * sWp1[h] + py * sWp1[16 + h] + pz * sWp1[32 + h];
            v = fmaxf(v * sPg[h] + sPb[h], 0.f);
        }
        aph[j] = (_Float16)v;
    }
    f32x4 pr[4];
#pragma unroll
    for (int f = 0; f < 4; f++) {
        f32x4 cini;
#pragma unroll
        for (int r = 0; r < 4; r++) cini[r] = bp2c[f];
        pr[f] = __builtin_amdgcn_mfma_f32_16x16x32_f16(aph, bP[f], cini,
                                                       0, 0, 0);
    }
    // ---- u = relu(bn1(xk - xq + pr)) -> scr(stride 72); v = xv + pr ----
    f32x4 vvr[4];
#pragma unroll
    for (int r = 0; r < 4; r++) {
#pragma unroll
        for (int f = 0; f < 4; f++) {
            float w0 = xkv[r][f] - xqv[f] + pr[f][r];
            float uu = fmaxf(w0 * g1c[f] + b1c[f], 0.f);
            scr[(g * 4 + r) * 72 + f * 16 + col] = (_Float16)uu;
            vvr[f][r] = xvv[r][f] + pr[f][r];
        }
    }
    // ---- GEMM1: o1 = relu(bn2(u @ W1)) ----
    f16x8 au[2];
#pragma unroll
    for (int kc = 0; kc < 2; kc++)
        au[kc] = *(const f16x8*)&scr[col * 72 + kc * 32 + g * 8];
    f32x4 acc1[8];
#pragma unroll
    for (int f = 0; f < 8; f++)
#pragma unroll
        for (int r = 0; r < 4; r++) acc1[f][r] = 0.f;
#pragma unroll
    for (int kc = 0; kc < 2; kc++) {
#pragma unroll
        for (int f = 0; f < 8; f++) {
            f16x8 bw = *(const f16x8*)
                &sW1t[(f * 16 + col) * 72 + kc * 32 + g * 8];
            acc1[f] = __builtin_amdgcn_mfma_f32_16x16x32_f16(au[kc], bw,
                                                             acc1[f], 0, 0, 0);
        }
    }
    // o1 -> scr (stride 136, aliases u region; u fully consumed above)
#pragma unroll
    for (int f = 0; f < 8; f++)
#pragma unroll
        for (int r = 0; r < 4; r++) {
            float o1 = fmaxf(acc1[f][r] * g2c[f] + b2c[f], 0.f);
            scr[(g * 4 + r) * 136 + f * 16 + col] = (_Float16)o1;
        }
    // ---- GEMM2: logits = o1 @ W2 + bw2 ----
    f16x8 ao[4];
#pragma unroll
    for (int kc = 0; kc < 4; kc++)
        ao[kc] = *(const f16x8*)&scr[col * 136 + kc * 32 + g * 8];
    f32x4 accL[4];
#pragma unroll
    for (int f = 0; f < 4; f++)
#pragma unroll
        for (int r = 0; r < 4; r++) accL[f][r] = bw2c[f];
#pragma unroll
    for (int kc = 0; kc < 4; kc++) {
#pragma unroll
        for (int f = 0; f < 4; f++) {
            f16x8 bw = *(const f16x8*)
                &sW2t[(f * 16 + col) * 136 + kc * 32 + g * 8];
            accL[f] = __builtin_amdgcn_mfma_f32_16x16x32_f16(ao[kc], bw,
                                                             accL[f], 0, 0, 0);
        }
    }
    // ---- softmax over s + einsum ----
    float outv[4];
#pragma unroll
    for (int f = 0; f < 4; f++) {
        float mx = fmaxf(fmaxf(accL[f][0], accL[f][1]),
                         fmaxf(accL[f][2], accL[f][3]));
        mx = fmaxf(mx, __shfl_xor(mx, 16, 64));
        mx = fmaxf(mx, __shfl_xor(mx, 32, 64));
        float sum = 0.f, part = 0.f;
#pragma unroll
        for (int r = 0; r < 4; r++) {
            float e = __expf(accL[f][r] - mx);
            sum += e;
            part = fmaf(e, vvr[f][r], part);
        }
        sum += __shfl_xor(sum, 16, 64);
        sum += __shfl_xor(sum, 32, 64);
        part += __shfl_xor(part, 16, 64);
        part += __shfl_xor(part, 32, 64);
        outv[f] = part / sum;
    }
    float val = (g == 0) ? outv[0]
              : (g == 1) ? outv[1]
              : (g == 2) ? outv[2] : outv[3];
    attn[q * 64 + lane] = val;
}

// ---------------------------------------------------------------------------
// K4a: h2 = relu(bn(relu(bn([feats,attn] @ Wc1)) @ Wc2))
// ---------------------------------------------------------------------------
__global__ __launch_bounds__(256) void head1_kernel(
    const float* __restrict__ feats, const float* __restrict__ attn,
    const float* __restrict__ Wc1, const float* __restrict__ cg1,
    const float* __restrict__ cb1, const float* __restrict__ Wc2,
    const float* __restrict__ cg2, const float* __restrict__ cb2,
    float* __restrict__ h2out)
{
    __shared__ float sWa[128 * 128];
    __shared__ float sWb[128 * 128];
    __shared__ float sh[16 * 132];
    __shared__ float sh1[16 * 132];
    __shared__ float sga[128], sba[128], sgb[128], sbb[128];
    const int t = threadIdx.x;
    const int row0 = blockIdx.x * 16;
    {
        const float4* a4 = (const float4*)Wc1;
        const float4* b4 = (const float4*)Wc2;
        float4* da = (float4*)sWa;
        float4* db = (float4*)sWb;
#pragma unroll
        for (int k = 0; k < 16; k++) {
            da[t + k * 256] = a4[t + k * 256];
            db[t + k * 256] = b4[t + k * 256];
        }
        if (t < 128) {
            sga[t] = cg1[t] * BN_INV; sba[t] = cb1[t];
            sgb[t] = cg2[t] * BN_INV; sbb[t] = cb2[t];
        }
    }
#pragma unroll
    for (int k = 0; k < 8; k++) {
        int e = t + k * 256;
        int r = e >> 7, c = e & 127;
        float xval = (c < 64) ? feats[(row0 + r) * 64 + c]
                              : attn[(row0 + r) * 64 + (c - 64)];
        sh[r * 132 + c] = xval;
    }
    __syncthreads();
    const int r = t >> 4, ob = (t & 15) * 4;
    {
        float acc[8];
#pragma unroll
        for (int i = 0; i < 8; i++) acc[i] = 0.f;
        const float* hrow = &sh[r * 132];
        for (int c = 0; c < 128; c++) {
            float hv = hrow[c];
#pragma unroll
            for (int i = 0; i < 2; i++) {
                const float* wr = &sWa[c * 128 + ob + 64 * i];
#pragma unroll
                for (int k = 0; k < 4; k++)
                    acc[i * 4 + k] = fmaf(hv, wr[k], acc[i * 4 + k]);
            }
        }
        float* h1row = &sh1[r * 132];
#pragma unroll
        for (int i = 0; i < 2; i++)
#pragma unroll
            for (int k = 0; k < 4; k++) {
                int o = ob + 64 * i + k;
                h1row[o] = fmaxf(acc[i * 4 + k] * sga[o] + sba[o], 0.f);
            }
    }
    __syncthreads();
    {
        float acc[8];
#pragma unroll
        for (int i = 0; i < 8; i++) acc[i] = 0.f;
        const float* hrow = &sh1[r * 132];
        for (int c = 0; c < 128; c++) {
            float hv = hrow[c];
#pragma unroll
            for (int i = 0; i < 2; i++) {
                const float* wr = &sWb[c * 128 + ob + 64 * i];
#pragma unroll
                for (int k = 0; k < 4; k++)
                    acc[i * 4 + k] = fmaf(hv, wr[k], acc[i * 4 + k]);
            }
        }
        float* dst = h2out + (row0 + r) * 128;
#pragma unroll
        for (int i = 0; i < 2; i++)
#pragma unroll
            for (int k = 0; k < 4; k++) {
                int o = ob + 64 * i + k;
                dst[o] = fmaxf(acc[i * 4 + k] * sgb[o] + sbb[o], 0.f);
            }
    }
}

// ---------------------------------------------------------------------------
// K4b: out = LN(h2 @ Wc3 + bc3)
// ---------------------------------------------------------------------------
__global__ __launch_bounds__(256) void head2_kernel(
    const float* __restrict__ h2, const float* __restrict__ Wc3,
    const float* __restrict__ bc3, const float* __restrict__ lng,
    const float* __restrict__ lnb, float* __restrict__ out)
{
    __shared__ float sW[128 * 64];
    __shared__ float sh[16 * 132];
    __shared__ float sg[64], sb[64], sbc[64];
    const int t = threadIdx.x;
    const int row0 = blockIdx.x * 16;
    {
        const float4* w4 = (const float4*)Wc3;
        float4* dw = (float4*)sW;
#pragma unroll
        for (int k = 0; k < 8; k++) dw[t + k * 256] = w4[t + k * 256];
        if (t < 64) { sg[t] = lng[t]; sb[t] = lnb[t]; sbc[t] = bc3[t]; }
        const float4* h4 = (const float4*)(h2 + row0 * 128);
#pragma unroll
        for (int k = 0; k < 2; k++) {
            int e = t + k * 256;
            int r = e >> 5, c4 = (e & 31) * 4;
            *(float4*)&sh[r * 132 + c4] = h4[e];
        }
    }
    __syncthreads();
    const int r = t >> 4, o0 = (t & 15) * 4;
    float acc[4] = {0.f, 0.f, 0.f, 0.f};
    const float* hrow = &sh[r * 132];
    for (int c = 0; c < 128; c++) {
        float hv = hrow[c];
        const float* wr = &sW[c * 64 + o0];
#pragma unroll
        for (int k = 0; k < 4; k++) acc[k] = fmaf(hv, wr[k], acc[k]);
    }
#pragma unroll
    for (int k = 0; k < 4; k++) acc[k] += sbc[o0 + k];
    float s1 = acc[0] + acc[1] + acc[2] + acc[3];
    float s2 = acc[0] * acc[0] + acc[1] * acc[1] + acc[2] * acc[2] +
               acc[3] * acc[3];
#pragma unroll
    for (int d = 1; d < 16; d <<= 1) {
        s1 += __shfl_xor(s1, d, 16);
        s2 += __shfl_xor(s2, d, 16);
    }
    float m = s1 * (1.f / 64.f);
    float var = s2 * (1.f / 64.f) - m * m;
    float inv = 1.f / sqrtf(var + LN_EPS);
    float* dst = out + (row0 + r) * 64;
#pragma unroll
    for (int k = 0; k < 4; k++) {
        int o = o0 + k;
        dst[o] = (acc[k] - m) * inv * sg[o] + sb[o];
    }
}

// ---------------------------------------------------------------------------
extern "C" void kernel_launch(void* const* d_in, const int* in_sizes, int n_in,
                              void* d_out, int out_size, void* d_ws,
                              size_t ws_size, hipStream_t stream)
{
    const int* indices = (const int*)d_in[0];
    const float* feats = (const float*)d_in[1];
    const float* Wq = (const float*)d_in[2];
    const float* bq = (const float*)d_in[3];
    const float* Wk = (const float*)d_in[4];
    const float* bk = (const float*)d_in[5];
    const float* Wv = (const float*)d_in[6];
    const float* bv = (const float*)d_in[7];
    const float* Wp1 = (const float*)d_in[8];
    const float* pg = (const float*)d_in[9];
    const float* pb = (const float*)d_in[10];
    const float* Wp2 = (const float*)d_in[11];
    const float* bp2 = (const float*)d_in[12];
    const float* wg1 = (const float*)d_in[13];
    const float* wb1 = (const float*)d_in[14];
    const float* Ww1 = (const float*)d_in[15];
    const float* wg2 = (const float*)d_in[16];
    const float* wb2 = (const float*)d_in[17];
    const float* Ww2 = (const float*)d_in[18];
    const float* bw2 = (const float*)d_in[19];
    const float* Wc1 = (const float*)d_in[20];
    const float* cg1 = (const float*)d_in[21];
    const float* cb1 = (const float*)d_in[22];
    const float* Wc2 = (const float*)d_in[23];
    const float* cg2 = (const float*)d_in[24];
    const float* cb2 = (const float*)d_in[25];
    const float* Wc3 = (const float*)d_in[26];
    const float* bc3 = (const float*)d_in[27];
    const float* lng = (const float*)d_in[28];
    const float* lnb = (const float*)d_in[29];

    float* out = (float*)d_out;
    float* ws = (float*)d_ws;
    float* xq = ws;
    float* xk = xq + N * C;
    float* xv = xk + N * C;
    float* attn = xv + N * C;
    float* h2 = attn + N * C;             // N*128 floats
    int* knn = (int*)(h2 + N * 2 * C);    // N*16 ints

    qkv_kernel<<<256, 256, 0, stream>>>(feats, Wq, bq, Wk, bk, Wv, bv, xq, xk,
                                        xv);
    knn_kernel<<<2048, 256, 0, stream>>>((const int4*)indices, knn);
    attn_kernel<<<1024, 512, 0, stream>>>((const int4*)indices, knn, xq, xk,
                                          xv, Wp1, pg, pb, Wp2, bp2, wg1, wb1,
                                          Ww1, wg2, wb2, Ww2, bw2, attn);
    head1_kernel<<<512, 256, 0, stream>>>(feats, attn, Wc1, cg1, cb1, Wc2,
                                          cg2, cb2, h2);
    head2_kernel<<<512, 256, 0, stream>>>(h2, Wc3, bc3, lng, lnb, out);
}

// Round 6
// 228.980 us; speedup vs baseline: 1.2084x; 1.0429x over previous
//
#include <hip/hip_runtime.h>

#define N 8192
#define C 64
#define S 16

static constexpr float BN_INV = 0.9999950000374997f; // 1/sqrt(1+1e-5)
static constexpr float LN_EPS = 1e-5f;

typedef _Float16 f16x8 __attribute__((ext_vector_type(8)));
typedef float f32x4 __attribute__((ext_vector_type(4)));

// ---------------------------------------------------------------------------
// K1: xq/xk/xv = feats @ W{q,k,v} + b  (8192x64 @ 64x64, f32)
// ---------------------------------------------------------------------------
__global__ __launch_bounds__(256) void qkv_kernel(
    const float* __restrict__ feats,
    const float* __restrict__ Wq, const float* __restrict__ bq,
    const float* __restrict__ Wk, const float* __restrict__ bk,
    const float* __restrict__ Wv, const float* __restrict__ bv,
    float* __restrict__ xq, float* __restrict__ xk, float* __restrict__ xv)
{
    __shared__ float sF[32 * 64];
    __shared__ float sW[3 * 64 * 64];
    const int t = threadIdx.x;
    const int row0 = blockIdx.x * 32;
    {
        const float4* src = (const float4*)(feats + row0 * 64);
        float4* dst = (float4*)sF;
        dst[t] = src[t];
        dst[t + 256] = src[t + 256];
        const float4* wq4 = (const float4*)Wq;
        const float4* wk4 = (const float4*)Wk;
        const float4* wv4 = (const float4*)Wv;
        float4* d0 = (float4*)sW;
        float4* d1 = (float4*)(sW + 4096);
        float4* d2 = (float4*)(sW + 8192);
#pragma unroll
        for (int k = 0; k < 4; k++) {
            d0[t + k * 256] = wq4[t + k * 256];
            d1[t + k * 256] = wk4[t + k * 256];
            d2[t + k * 256] = wv4[t + k * 256];
        }
    }
    __syncthreads();
    const int col = t & 63, rg = t >> 6;
    const float* biases[3] = {bq, bk, bv};
    float* outs[3] = {xq, xk, xv};
    for (int m = 0; m < 3; m++) {
        const float* w = sW + m * 4096;
        float bias = biases[m][col];
        float acc[8];
#pragma unroll
        for (int k = 0; k < 8; k++) acc[k] = bias;
        for (int c = 0; c < 64; c++) {
            float wv = w[c * 64 + col];
#pragma unroll
            for (int k = 0; k < 8; k++)
                acc[k] = fmaf(sF[(rg * 8 + k) * 64 + c], wv, acc[k]);
        }
        float* o = outs[m] + row0 * 64;
#pragma unroll
        for (int k = 0; k < 8; k++) o[(rg * 8 + k) * 64 + col] = acc[k];
    }
}

// ---------------------------------------------------------------------------
// K2: exact 16-NN. Whole cloud packed (x|y<<8|z<<16, coords<128) in 32KB LDS,
// loaded once -> ZERO barriers in the scan (R5 was barrier/LDS-bound at 45%
// VALUBusy). d2 via v_dot4_u32_u8: d2 = udot4(p,p,qq) - udot4(p,2q,0).
// Top-4/lane sorted insert (7 ops), width-64 tournament merge, exact-check
// fallback (full 16-deep rescan from global) as in R5.
// ---------------------------------------------------------------------------
__device__ __forceinline__ void sort2(unsigned& x, unsigned& y)
{
    unsigned lo = min(x, y);
    unsigned hi = max(x, y);
    x = lo;
    y = hi;
}

__global__ __launch_bounds__(512) void knn_kernel(
    const int4* __restrict__ idx4, int* __restrict__ knn_out)
{
    __shared__ unsigned pk[8192]; // 32KB packed cloud
    const int t = threadIdx.x;
    const int lane = t & 63;
    const int wv = t >> 6;
    const int q = blockIdx.x * 8 + wv;
#pragma unroll
    for (int i = 0; i < 16; i++) {
        int j = i * 512 + t;
        int4 c = idx4[j];
        pk[j] = (unsigned)c.y | ((unsigned)c.z << 8) | ((unsigned)c.w << 16);
    }
    const int4 qc = idx4[q];
    const int qx = qc.y, qy = qc.z, qz = qc.w;
    const unsigned qq = (unsigned)(qx * qx + qy * qy + qz * qz);
#if __has_builtin(__builtin_amdgcn_udot4)
    const unsigned qpk2 = (unsigned)(2 * qx) | ((unsigned)(2 * qy) << 8) |
                          ((unsigned)(2 * qz) << 16);
#endif
    unsigned a0 = 0xFFFFFFFFu, a1 = 0xFFFFFFFFu, a2 = 0xFFFFFFFFu,
             a3 = 0xFFFFFFFFu;
    __syncthreads();
#pragma unroll 4
    for (int i = 0; i < 128; ++i) {
        int j = i * 64 + lane;
        unsigned p = pk[j];
#if __has_builtin(__builtin_amdgcn_udot4)
        unsigned pp = __builtin_amdgcn_udot4(p, p, qq, false);
        unsigned pq2 = __builtin_amdgcn_udot4(p, qpk2, 0u, false);
        unsigned d2 = pp - pq2;
#else
        int x = (int)(p & 255u), y = (int)((p >> 8) & 255u),
            z = (int)(p >> 16);
        int dx = x - qx, dy = y - qy, dz = z - qz;
        unsigned d2 = (unsigned)(dx * dx + dy * dy + dz * dz);
#endif
        unsigned key = (d2 << 13) + (unsigned)j;
        a3 = min(a3, key);
        sort2(a2, a3);
        sort2(a1, a2);
        sort2(a0, a1);
    }
    const unsigned a3pre = a3;
    unsigned g16 = 0;
    for (int r = 0; r < 16; ++r) {
        unsigned m = a0;
        m = min(m, (unsigned)__shfl_xor((int)m, 1, 64));
        m = min(m, (unsigned)__shfl_xor((int)m, 2, 64));
        m = min(m, (unsigned)__shfl_xor((int)m, 4, 64));
        m = min(m, (unsigned)__shfl_xor((int)m, 8, 64));
        m = min(m, (unsigned)__shfl_xor((int)m, 16, 64));
        m = min(m, (unsigned)__shfl_xor((int)m, 32, 64));
        if (lane == r) knn_out[q * 16 + r] = (int)(m & 8191u);
        bool win = (a0 == m);
        a0 = win ? a1 : a0;
        a1 = win ? a2 : a1;
        a2 = win ? a3 : a2;
        a3 = win ? 0xFFFFFFFFu : a3;
        g16 = m;
    }
    // exactness: bad iff some lane might have dropped a key < global 16th
    unsigned long long bad = __ballot(a3pre < g16);
    if (bad) {
        unsigned b0 = 0xFFFFFFFFu, b1 = 0xFFFFFFFFu, b2 = 0xFFFFFFFFu,
                 b3 = 0xFFFFFFFFu, b4 = 0xFFFFFFFFu, b5 = 0xFFFFFFFFu,
                 b6 = 0xFFFFFFFFu, b7 = 0xFFFFFFFFu, b8 = 0xFFFFFFFFu,
                 b9 = 0xFFFFFFFFu, b10 = 0xFFFFFFFFu, b11 = 0xFFFFFFFFu,
                 b12 = 0xFFFFFFFFu, b13 = 0xFFFFFFFFu, b14 = 0xFFFFFFFFu,
                 b15 = 0xFFFFFFFFu;
        for (int i = 0; i < 128; ++i) {
            int j = i * 64 + lane;
            int4 cd = idx4[j];
            int dx = cd.y - qx, dy = cd.z - qy, dz = cd.w - qz;
            unsigned d2 = (unsigned)(dx * dx + dy * dy + dz * dz);
            unsigned key = (d2 << 13) + (unsigned)j;
            b15 = min(b15, key);
            sort2(b14, b15); sort2(b13, b14); sort2(b12, b13);
            sort2(b11, b12); sort2(b10, b11); sort2(b9, b10);
            sort2(b8, b9);   sort2(b7, b8);   sort2(b6, b7);
            sort2(b5, b6);   sort2(b4, b5);   sort2(b3, b4);
            sort2(b2, b3);   sort2(b1, b2);   sort2(b0, b1);
        }
        for (int r = 0; r < 16; ++r) {
            unsigned m = b0;
            m = min(m, (unsigned)__shfl_xor((int)m, 1, 64));
            m = min(m, (unsigned)__shfl_xor((int)m, 2, 64));
            m = min(m, (unsigned)__shfl_xor((int)m, 4, 64));
            m = min(m, (unsigned)__shfl_xor((int)m, 8, 64));
            m = min(m, (unsigned)__shfl_xor((int)m, 16, 64));
            m = min(m, (unsigned)__shfl_xor((int)m, 32, 64));
            if (lane == r) knn_out[q * 16 + r] = (int)(m & 8191u);
            bool win = (b0 == m);
            b0 = win ? b1 : b0;    b1 = win ? b2 : b1;
            b2 = win ? b3 : b2;    b3 = win ? b4 : b3;
            b4 = win ? b5 : b4;    b5 = win ? b6 : b5;
            b6 = win ? b7 : b6;    b7 = win ? b8 : b7;
            b8 = win ? b9 : b8;    b9 = win ? b10 : b9;
            b10 = win ? b11 : b10; b11 = win ? b12 : b11;
            b12 = win ? b13 : b12; b13 = win ? b14 : b13;
            b14 = win ? b15 : b14; b15 = win ? 0xFFFFFFFFu : b15;
        }
    }
}

// ---------------------------------------------------------------------------
// K3: MFMA vector-attention. 1024 blocks x 512 thr; one query per 64-lane
// wave, 8 waves/block. (unchanged from R5)
// ---------------------------------------------------------------------------
__global__ __launch_bounds__(512, 4) void attn_kernel(
    const int4* __restrict__ idx4, const int* __restrict__ knn,
    const float* __restrict__ xq, const float* __restrict__ xk,
    const float* __restrict__ xv,
    const float* __restrict__ Wp1, const float* __restrict__ pg,
    const float* __restrict__ pb, const float* __restrict__ Wp2,
    const float* __restrict__ bp2,
    const float* __restrict__ wg1, const float* __restrict__ wb1,
    const float* __restrict__ Ww1,
    const float* __restrict__ wg2, const float* __restrict__ wb2,
    const float* __restrict__ Ww2, const float* __restrict__ bw2,
    float* __restrict__ attn)
{
    __shared__ _Float16 sW1t[128 * 72];
    __shared__ _Float16 sW2t[64 * 136];
    __shared__ _Float16 sscr[8][16 * 136];
    __shared__ float sWp1[48], sPg[16], sPb[16];

    const int t = threadIdx.x;
    const int lane = t & 63;
    const int wv = t >> 6;
    const int col = lane & 15, g = lane >> 4;
    const int q = blockIdx.x * 8 + wv;

    const int jA = knn[q * 16 + col];
    const int4 jC = *(const int4*)(knn + q * 16 + g * 4);
    const int jr[4] = {jC.x, jC.y, jC.z, jC.w};
    const int4 pc = idx4[jA];
    const int4 qc = idx4[q];
    float xqv[4], xkv[4][4], xvv[4][4];
#pragma unroll
    for (int f = 0; f < 4; f++) xqv[f] = xq[q * 64 + f * 16 + col];
#pragma unroll
    for (int r = 0; r < 4; r++)
#pragma unroll
        for (int f = 0; f < 4; f++) {
            xkv[r][f] = xk[jr[r] * 64 + f * 16 + col];
            xvv[r][f] = xv[jr[r] * 64 + f * 16 + col];
        }

    for (int e = t; e < 8192; e += 512) {
        int c = e >> 7, o = e & 127;
        sW1t[o * 72 + c] = (_Float16)Ww1[e];
    }
    for (int e = t; e < 8192; e += 512) {
        int n = e >> 6, m = e & 63;
        sW2t[m * 136 + n] = (_Float16)Ww2[e];
    }
    if (t < 48) sWp1[t] = Wp1[t];
    if (t < 16) { sPg[t] = pg[t] * BN_INV; sPb[t] = pb[t]; }

    float g1c[4], b1c[4], bp2c[4], bw2c[4], g2c[8], b2c[8];
#pragma unroll
    for (int f = 0; f < 4; f++) {
        int c = f * 16 + col;
        g1c[f] = wg1[c] * BN_INV; b1c[f] = wb1[c];
        bp2c[f] = bp2[c]; bw2c[f] = bw2[c];
    }
#pragma unroll
    for (int f = 0; f < 8; f++) {
        int o = f * 16 + col;
        g2c[f] = wg2[o] * BN_INV; b2c[f] = wb2[o];
    }
    f16x8 bP[4];
#pragma unroll
    for (int f = 0; f < 4; f++) {
#pragma unroll
        for (int j = 0; j < 8; j++) {
            int h = g * 8 + j;
            bP[f][j] = (g < 2) ? (_Float16)Wp2[h * 64 + f * 16 + col]
                               : (_Float16)0.f;
        }
    }
    __syncthreads();

    _Float16* scr = sscr[wv];

    const float px = (float)(pc.y - qc.y);
    const float py = (float)(pc.z - qc.z);
    const float pz = (float)(pc.w - qc.w);
    f16x8 aph;
#pragma unroll
    for (int j = 0; j < 8; j++) {
        int h = g * 8 + j;
        float v = 0.f;
        if (g < 2) {
            v = px * sWp1[h] + py * sWp1[16 + h] + pz * sWp1[32 + h];
            v = fmaxf(v * sPg[h] + sPb[h], 0.f);
        }
        aph[j] = (_Float16)v;
    }
    f32x4 pr[4];
#pragma unroll
    for (int f = 0; f < 4; f++) {
        f32x4 cini;
#pragma unroll
        for (int r = 0; r < 4; r++) cini[r] = bp2c[f];
        pr[f] = __builtin_amdgcn_mfma_f32_16x16x32_f16(aph, bP[f], cini,
                                                       0, 0, 0);
    }
    f32x4 vvr[4];
#pragma unroll
    for (int r = 0; r < 4; r++) {
#pragma unroll
        for (int f = 0; f < 4; f++) {
            float w0 = xkv[r][f] - xqv[f] + pr[f][r];
            float uu = fmaxf(w0 * g1c[f] + b1c[f], 0.f);
            scr[(g * 4 + r) * 72 + f * 16 + col] = (_Float16)uu;
            vvr[f][r] = xvv[r][f] + pr[f][r];
        }
    }
    f16x8 au[2];
#pragma unroll
    for (int kc = 0; kc < 2; kc++)
        au[kc] = *(const f16x8*)&scr[col * 72 + kc * 32 + g * 8];
    f32x4 acc1[8];
#pragma unroll
    for (int f = 0; f < 8; f++)
#pragma unroll
        for (int r = 0; r < 4; r++) acc1[f][r] = 0.f;
#pragma unroll
    for (int kc = 0; kc < 2; kc++) {
#pragma unroll
        for (int f = 0; f < 8; f++) {
            f16x8 bw = *(const f16x8*)
                &sW1t[(f * 16 + col) * 72 + kc * 32 + g * 8];
            acc1[f] = __builtin_amdgcn_mfma_f32_16x16x32_f16(au[kc], bw,
                                                             acc1[f], 0, 0, 0);
        }
    }
#pragma unroll
    for (int f = 0; f < 8; f++)
#pragma unroll
        for (int r = 0; r < 4; r++) {
            float o1 = fmaxf(acc1[f][r] * g2c[f] + b2c[f], 0.f);
            scr[(g * 4 + r) * 136 + f * 16 + col] = (_Float16)o1;
        }
    f16x8 ao[4];
#pragma unroll
    for (int kc = 0; kc < 4; kc++)
        ao[kc] = *(const f16x8*)&scr[col * 136 + kc * 32 + g * 8];
    f32x4 accL[4];
#pragma unroll
    for (int f = 0; f < 4; f++)
#pragma unroll
        for (int r = 0; r < 4; r++) accL[f][r] = bw2c[f];
#pragma unroll
    for (int kc = 0; kc < 4; kc++) {
#pragma unroll
        for (int f = 0; f < 4; f++) {
            f16x8 bw = *(const f16x8*)
                &sW2t[(f * 16 + col) * 136 + kc * 32 + g * 8];
            accL[f] = __builtin_amdgcn_mfma_f32_16x16x32_f16(ao[kc], bw,
                                                             accL[f], 0, 0, 0);
        }
    }
    float outv[4];
#pragma unroll
    for (int f = 0; f < 4; f++) {
        float mx = fmaxf(fmaxf(accL[f][0], accL[f][1]),
                         fmaxf(accL[f][2], accL[f][3]));
        mx = fmaxf(mx, __shfl_xor(mx, 16, 64));
        mx = fmaxf(mx, __shfl_xor(mx, 32, 64));
        float sum = 0.f, part = 0.f;
#pragma unroll
        for (int r = 0; r < 4; r++) {
            float e = __expf(accL[f][r] - mx);
            sum += e;
            part = fmaf(e, vvr[f][r], part);
        }
        sum += __shfl_xor(sum, 16, 64);
        sum += __shfl_xor(sum, 32, 64);
        part += __shfl_xor(part, 16, 64);
        part += __shfl_xor(part, 32, 64);
        outv[f] = part / sum;
    }
    float val = (g == 0) ? outv[0]
              : (g == 1) ? outv[1]
              : (g == 2) ? outv[2] : outv[3];
    attn[q * 64 + lane] = val;
}

// ---------------------------------------------------------------------------
// K4: FUSED head: out = LN(relu(bn(relu(bn([feats,attn]@Wc1))@Wc2))@Wc3+bc3)
// Wc3 staged into sWa's slot during phase 2 (Wc1 dead after phase 1); h2
// round-trips through LDS (reuses sh). Kills the former head2 dispatch and
// its 8MB HBM round-trip.
// ---------------------------------------------------------------------------
__global__ __launch_bounds__(256) void head_kernel(
    const float* __restrict__ feats, const float* __restrict__ attn,
    const float* __restrict__ Wc1, const float* __restrict__ cg1,
    const float* __restrict__ cb1, const float* __restrict__ Wc2,
    const float* __restrict__ cg2, const float* __restrict__ cb2,
    const float* __restrict__ Wc3, const float* __restrict__ bc3,
    const float* __restrict__ lng, const float* __restrict__ lnb,
    float* __restrict__ out)
{
    __shared__ float sWa[128 * 128];
    __shared__ float sWb[128 * 128];
    __shared__ float sh[16 * 132];
    __shared__ float sh1[16 * 132];
    __shared__ float sga[128], sba[128], sgb[128], sbb[128];
    __shared__ float sbc3[64], slng[64], slnb[64];
    const int t = threadIdx.x;
    const int row0 = blockIdx.x * 16;
    {
        const float4* a4 = (const float4*)Wc1;
        const float4* b4 = (const float4*)Wc2;
        float4* da = (float4*)sWa;
        float4* db = (float4*)sWb;
#pragma unroll
        for (int k = 0; k < 16; k++) {
            da[t + k * 256] = a4[t + k * 256];
            db[t + k * 256] = b4[t + k * 256];
        }
        if (t < 128) {
            sga[t] = cg1[t] * BN_INV; sba[t] = cb1[t];
            sgb[t] = cg2[t] * BN_INV; sbb[t] = cb2[t];
        }
        if (t >= 128 && t < 192) {
            int o = t - 128;
            sbc3[o] = bc3[o]; slng[o] = lng[o]; slnb[o] = lnb[o];
        }
    }
#pragma unroll
    for (int k = 0; k < 8; k++) {
        int e = t + k * 256;
        int r = e >> 7, c = e & 127;
        float xval = (c < 64) ? feats[(row0 + r) * 64 + c]
                              : attn[(row0 + r) * 64 + (c - 64)];
        sh[r * 132 + c] = xval;
    }
    __syncthreads();
    const int r = t >> 4, ob = (t & 15) * 4;
    // Phase 1: h1 = relu(bn(h @ Wc1)) -> sh1
    {
        float acc[8];
#pragma unroll
        for (int i = 0; i < 8; i++) acc[i] = 0.f;
        const float* hrow = &sh[r * 132];
        for (int c = 0; c < 128; c++) {
            float hv = hrow[c];
#pragma unroll
            for (int i = 0; i < 2; i++) {
                const float* wr = &sWa[c * 128 + ob + 64 * i];
#pragma unroll
                for (int k = 0; k < 4; k++)
                    acc[i * 4 + k] = fmaf(hv, wr[k], acc[i * 4 + k]);
            }
        }
        float* h1row = &sh1[r * 132];
#pragma unroll
        for (int i = 0; i < 2; i++)
#pragma unroll
            for (int k = 0; k < 4; k++) {
                int o = ob + 64 * i + k;
                h1row[o] = fmaxf(acc[i * 4 + k] * sga[o] + sba[o], 0.f);
            }
    }
    __syncthreads();
    // Phase 2: h2 = relu(bn(h1 @ Wc2)) -> sh (reuse); stage Wc3 -> sWa
    {
        float acc[8];
#pragma unroll
        for (int i = 0; i < 8; i++) acc[i] = 0.f;
        const float* hrow = &sh1[r * 132];
        for (int c = 0; c < 128; c++) {
            float hv = hrow[c];
#pragma unroll
            for (int i = 0; i < 2; i++) {
                const float* wr = &sWb[c * 128 + ob + 64 * i];
#pragma unroll
                for (int k = 0; k < 4; k++)
                    acc[i * 4 + k] = fmaf(hv, wr[k], acc[i * 4 + k]);
            }
        }
        {
            const float4* w4 = (const float4*)Wc3;
            float4* dw = (float4*)sWa;
#pragma unroll
            for (int k = 0; k < 8; k++) dw[t + k * 256] = w4[t + k * 256];
        }
        float* h2row = &sh[r * 132];
#pragma unroll
        for (int i = 0; i < 2; i++)
#pragma unroll
            for (int k = 0; k < 4; k++) {
                int o = ob + 64 * i + k;
                h2row[o] = fmaxf(acc[i * 4 + k] * sgb[o] + sbb[o], 0.f);
            }
    }
    __syncthreads();
    // Phase 3: out = LN(h2 @ Wc3 + bc3)
    {
        const int o0 = (t & 15) * 4;
        float acc[4];
#pragma unroll
        for (int k = 0; k < 4; k++) acc[k] = sbc3[o0 + k];
        const float* hrow = &sh[r * 132];
        for (int c = 0; c < 128; c++) {
            float hv = hrow[c];
            const float* wr = &sWa[c * 64 + o0];
#pragma unroll
            for (int k = 0; k < 4; k++) acc[k] = fmaf(hv, wr[k], acc[k]);
        }
        float s1 = acc[0] + acc[1] + acc[2] + acc[3];
        float s2 = acc[0] * acc[0] + acc[1] * acc[1] + acc[2] * acc[2] +
                   acc[3] * acc[3];
#pragma unroll
        for (int d = 1; d < 16; d <<= 1) {
            s1 += __shfl_xor(s1, d, 16);
            s2 += __shfl_xor(s2, d, 16);
        }
        float m = s1 * (1.f / 64.f);
        float var = s2 * (1.f / 64.f) - m * m;
        float inv = 1.f / sqrtf(var + LN_EPS);
        float* dst = out + (row0 + r) * 64;
#pragma unroll
        for (int k = 0; k < 4; k++) {
            int o = o0 + k;
            dst[o] = (acc[k] - m) * inv * slng[o] + slnb[o];
        }
    }
}

// ---------------------------------------------------------------------------
extern "C" void kernel_launch(void* const* d_in, const int* in_sizes, int n_in,
                              void* d_out, int out_size, void* d_ws,
                              size_t ws_size, hipStream_t stream)
{
    const int* indices = (const int*)d_in[0];
    const float* feats = (const float*)d_in[1];
    const float* Wq = (const float*)d_in[2];
    const float* bq = (const float*)d_in[3];
    const float* Wk = (const float*)d_in[4];
    const float* bk = (const float*)d_in[5];
    const float* Wv = (const float*)d_in[6];
    const float* bv = (const float*)d_in[7];
    const float* Wp1 = (const float*)d_in[8];
    const float* pg = (const float*)d_in[9];
    const float* pb = (const float*)d_in[10];
    const float* Wp2 = (const float*)d_in[11];
    const float* bp2 = (const float*)d_in[12];
    const float* wg1 = (const float*)d_in[13];
    const float* wb1 = (const float*)d_in[14];
    const float* Ww1 = (const float*)d_in[15];
    const float* wg2 = (const float*)d_in[16];
    const float* wb2 = (const float*)d_in[17];
    const float* Ww2 = (const float*)d_in[18];
    const float* bw2 = (const float*)d_in[19];
    const float* Wc1 = (const float*)d_in[20];
    const float* cg1 = (const float*)d_in[21];
    const float* cb1 = (const float*)d_in[22];
    const float* Wc2 = (const float*)d_in[23];
    const float* cg2 = (const float*)d_in[24];
    const float* cb2 = (const float*)d_in[25];
    const float* Wc3 = (const float*)d_in[26];
    const float* bc3 = (const float*)d_in[27];
    const float* lng = (const float*)d_in[28];
    const float* lnb = (const float*)d_in[29];

    float* out = (float*)d_out;
    float* ws = (float*)d_ws;
    float* xq = ws;
    float* xk = xq + N * C;
    float* xv = xk + N * C;
    float* attn = xv + N * C;
    int* knn = (int*)(attn + N * C);      // N*16 ints

    qkv_kernel<<<256, 256, 0, stream>>>(feats, Wq, bq, Wk, bk, Wv, bv, xq, xk,
                                        xv);
    knn_kernel<<<1024, 512, 0, stream>>>((const int4*)indices, knn);
    attn_kernel<<<1024, 512, 0, stream>>>((const int4*)indices, knn, xq, xk,
                                          xv, Wp1, pg, pb, Wp2, bp2, wg1, wb1,
                                          Ww1, wg2, wb2, Ww2, bw2, attn);
    head_kernel<<<512, 256, 0, stream>>>(feats, attn, Wc1, cg1, cb1, Wc2, cg2,
                                         cb2, Wc3, bc3, lng, lnb, out);
}

// Round 7
// 201.645 us; speedup vs baseline: 1.3722x; 1.1356x over previous
//
#include <hip/hip_runtime.h>

#define N 8192
#define C 64
#define S 16

static constexpr float BN_INV = 0.9999950000374997f; // 1/sqrt(1+1e-5)
static constexpr float LN_EPS = 1e-5f;

typedef _Float16 f16x8 __attribute__((ext_vector_type(8)));
typedef float f32x4 __attribute__((ext_vector_type(4)));

__device__ __forceinline__ void sort2(unsigned& x, unsigned& y)
{
    unsigned lo = min(x, y);
    unsigned hi = max(x, y);
    x = lo;
    y = hi;
}

// ---------------------------------------------------------------------------
// K1: FUSED knn + qkv. Blocks [0,1024): exact 16-NN (one query/wave, packed
// cloud in 32KB dynamic LDS, TWO independent top-4 chains per lane for ILP,
// sorted merge + tournament + exact fallback). Blocks [1024,1088): MFMA-f16
// qkv (x{q,k,v} = feats @ W + b), 128 rows/block, weights as B-frags in the
// same dynamic LDS. knn is latency-bound (39% VALU R6) -> qkv rides free.
// ---------------------------------------------------------------------------
__global__ __launch_bounds__(512) void qkv_knn_kernel(
    const int4* __restrict__ idx4, int* __restrict__ knn_out,
    const float* __restrict__ feats,
    const float* __restrict__ Wq, const float* __restrict__ bq,
    const float* __restrict__ Wk, const float* __restrict__ bk,
    const float* __restrict__ Wv, const float* __restrict__ bv,
    float* __restrict__ xq, float* __restrict__ xk, float* __restrict__ xv)
{
    extern __shared__ char smem[];
    const int t = threadIdx.x;
    const int lane = t & 63;
    const int wv = t >> 6;
    if (blockIdx.x < 1024) {
        // ---------------- KNN branch ----------------
        unsigned* pk = (unsigned*)smem; // 32KB packed cloud
        const int q = blockIdx.x * 8 + wv;
#pragma unroll
        for (int i = 0; i < 16; i++) {
            int j = i * 512 + t;
            int4 c = idx4[j];
            pk[j] = (unsigned)c.y | ((unsigned)c.z << 8) |
                    ((unsigned)c.w << 16);
        }
        const int4 qc = idx4[q];
        const int qx = qc.y, qy = qc.z, qz = qc.w;
        const unsigned qq = (unsigned)(qx * qx + qy * qy + qz * qz);
#if __has_builtin(__builtin_amdgcn_udot4)
        const unsigned qpk2 = (unsigned)(2 * qx) | ((unsigned)(2 * qy) << 8) |
                              ((unsigned)(2 * qz) << 16);
#endif
        unsigned a0 = 0xFFFFFFFFu, a1 = 0xFFFFFFFFu, a2 = 0xFFFFFFFFu,
                 a3 = 0xFFFFFFFFu;
        unsigned b0 = 0xFFFFFFFFu, b1 = 0xFFFFFFFFu, b2 = 0xFFFFFFFFu,
                 b3 = 0xFFFFFFFFu;
        __syncthreads();
#pragma unroll 4
        for (int i = 0; i < 64; ++i) {
            int jA = i * 64 + lane;
            int jB = (i + 64) * 64 + lane;
            unsigned pA = pk[jA];
            unsigned pB = pk[jB];
#if __has_builtin(__builtin_amdgcn_udot4)
            unsigned d2A = __builtin_amdgcn_udot4(pA, pA, qq, false) -
                           __builtin_amdgcn_udot4(pA, qpk2, 0u, false);
            unsigned d2B = __builtin_amdgcn_udot4(pB, pB, qq, false) -
                           __builtin_amdgcn_udot4(pB, qpk2, 0u, false);
#else
            int xa = (int)(pA & 255u), ya = (int)((pA >> 8) & 255u),
                za = (int)(pA >> 16);
            int xb = (int)(pB & 255u), yb = (int)((pB >> 8) & 255u),
                zb = (int)(pB >> 16);
            int dxa = xa - qx, dya = ya - qy, dza = za - qz;
            int dxb = xb - qx, dyb = yb - qy, dzb = zb - qz;
            unsigned d2A = (unsigned)(dxa * dxa + dya * dya + dza * dza);
            unsigned d2B = (unsigned)(dxb * dxb + dyb * dyb + dzb * dzb);
#endif
            unsigned keyA = (d2A << 13) + (unsigned)jA;
            unsigned keyB = (d2B << 13) + (unsigned)jB;
            a3 = min(a3, keyA);
            sort2(a2, a3); sort2(a1, a2); sort2(a0, a1);
            b3 = min(b3, keyB);
            sort2(b2, b3); sort2(b1, b2); sort2(b0, b1);
        }
        // merge two sorted-4 lists -> smallest 4 of the 8
        unsigned t0 = min(a0, b3), t1 = min(a1, b2), t2 = min(a2, b1),
                 t3 = min(a3, b0);
        sort2(t0, t2); sort2(t1, t3); sort2(t0, t1); sort2(t2, t3);
        sort2(t1, t2);
        const unsigned t3pre = t3; // every dropped key >= t3 (<= min(a3,b3))
        unsigned g16 = 0;
        for (int r = 0; r < 16; ++r) {
            unsigned m = t0;
            m = min(m, (unsigned)__shfl_xor((int)m, 1, 64));
            m = min(m, (unsigned)__shfl_xor((int)m, 2, 64));
            m = min(m, (unsigned)__shfl_xor((int)m, 4, 64));
            m = min(m, (unsigned)__shfl_xor((int)m, 8, 64));
            m = min(m, (unsigned)__shfl_xor((int)m, 16, 64));
            m = min(m, (unsigned)__shfl_xor((int)m, 32, 64));
            if (lane == r) knn_out[q * 16 + r] = (int)(m & 8191u);
            bool win = (t0 == m);
            t0 = win ? t1 : t0;
            t1 = win ? t2 : t1;
            t2 = win ? t3 : t2;
            t3 = win ? 0xFFFFFFFFu : t3;
            g16 = m;
        }
        unsigned long long bad = __ballot(t3pre < g16);
        if (bad) {
            unsigned c0 = 0xFFFFFFFFu, c1 = 0xFFFFFFFFu, c2 = 0xFFFFFFFFu,
                     c3 = 0xFFFFFFFFu, c4 = 0xFFFFFFFFu, c5 = 0xFFFFFFFFu,
                     c6 = 0xFFFFFFFFu, c7 = 0xFFFFFFFFu, c8 = 0xFFFFFFFFu,
                     c9 = 0xFFFFFFFFu, c10 = 0xFFFFFFFFu, c11 = 0xFFFFFFFFu,
                     c12 = 0xFFFFFFFFu, c13 = 0xFFFFFFFFu, c14 = 0xFFFFFFFFu,
                     c15 = 0xFFFFFFFFu;
            for (int i = 0; i < 128; ++i) {
                int j = i * 64 + lane;
                int4 cd = idx4[j];
                int dx = cd.y - qx, dy = cd.z - qy, dz = cd.w - qz;
                unsigned d2 = (unsigned)(dx * dx + dy * dy + dz * dz);
                unsigned key = (d2 << 13) + (unsigned)j;
                c15 = min(c15, key);
                sort2(c14, c15); sort2(c13, c14); sort2(c12, c13);
                sort2(c11, c12); sort2(c10, c11); sort2(c9, c10);
                sort2(c8, c9);   sort2(c7, c8);   sort2(c6, c7);
                sort2(c5, c6);   sort2(c4, c5);   sort2(c3, c4);
                sort2(c2, c3);   sort2(c1, c2);   sort2(c0, c1);
            }
            for (int r = 0; r < 16; ++r) {
                unsigned m = c0;
                m = min(m, (unsigned)__shfl_xor((int)m, 1, 64));
                m = min(m, (unsigned)__shfl_xor((int)m, 2, 64));
                m = min(m, (unsigned)__shfl_xor((int)m, 4, 64));
                m = min(m, (unsigned)__shfl_xor((int)m, 8, 64));
                m = min(m, (unsigned)__shfl_xor((int)m, 16, 64));
                m = min(m, (unsigned)__shfl_xor((int)m, 32, 64));
                if (lane == r) knn_out[q * 16 + r] = (int)(m & 8191u);
                bool win = (c0 == m);
                c0 = win ? c1 : c0;    c1 = win ? c2 : c1;
                c2 = win ? c3 : c2;    c3 = win ? c4 : c3;
                c4 = win ? c5 : c4;    c5 = win ? c6 : c5;
                c6 = win ? c7 : c6;    c7 = win ? c8 : c7;
                c8 = win ? c9 : c8;    c9 = win ? c10 : c9;
                c10 = win ? c11 : c10; c11 = win ? c12 : c11;
                c12 = win ? c13 : c12; c13 = win ? c14 : c13;
                c14 = win ? c15 : c14; c15 = win ? 0xFFFFFFFFu : c15;
            }
        }
    } else {
        // ---------------- QKV branch (MFMA f16) ----------------
        _Float16* sBt = (_Float16*)smem;          // [192][72] B-frags
        float* sbias = (float*)(smem + 192 * 72 * 2); // [192]
        const int col = lane & 15, g = lane >> 4;
        const int bid2 = blockIdx.x - 1024;
        const int row0w = bid2 * 128 + wv * 16;
        // stage W{q,k,v} transposed to f16 B-frags: sBt[n][k], n=m*64+o
        {
            const float* Ws[3] = {Wq, Wk, Wv};
#pragma unroll
            for (int m = 0; m < 3; m++) {
                int k = t >> 3, nb = (t & 7) * 8;
                const float4* src = (const float4*)(Ws[m] + k * 64 + nb);
                float4 w0 = src[0], w1 = src[1];
                _Float16* dst = &sBt[(m * 64 + nb) * 72 + k];
                dst[0 * 72] = (_Float16)w0.x; dst[1 * 72] = (_Float16)w0.y;
                dst[2 * 72] = (_Float16)w0.z; dst[3 * 72] = (_Float16)w0.w;
                dst[4 * 72] = (_Float16)w1.x; dst[5 * 72] = (_Float16)w1.y;
                dst[6 * 72] = (_Float16)w1.z; dst[7 * 72] = (_Float16)w1.w;
            }
            if (t < 64) sbias[t] = bq[t];
            else if (t < 128) sbias[t] = bk[t - 64];
            else if (t < 192) sbias[t] = bv[t - 128];
        }
        __syncthreads();
        // A-frags from feats
        f16x8 au[2];
#pragma unroll
        for (int kc = 0; kc < 2; kc++) {
            const float4* src = (const float4*)
                (feats + (row0w + col) * 64 + kc * 32 + g * 8);
            float4 v0 = src[0], v1 = src[1];
            au[kc][0] = (_Float16)v0.x; au[kc][1] = (_Float16)v0.y;
            au[kc][2] = (_Float16)v0.z; au[kc][3] = (_Float16)v0.w;
            au[kc][4] = (_Float16)v1.x; au[kc][5] = (_Float16)v1.y;
            au[kc][6] = (_Float16)v1.z; au[kc][7] = (_Float16)v1.w;
        }
        float* outs[3] = {xq, xk, xv};
#pragma unroll
        for (int f = 0; f < 12; f++) {
            f32x4 acc;
            float bias = sbias[f * 16 + col];
#pragma unroll
            for (int r = 0; r < 4; r++) acc[r] = bias;
#pragma unroll
            for (int kc = 0; kc < 2; kc++) {
                f16x8 bw = *(const f16x8*)
                    &sBt[(f * 16 + col) * 72 + kc * 32 + g * 8];
                acc = __builtin_amdgcn_mfma_f32_16x16x32_f16(au[kc], bw, acc,
                                                             0, 0, 0);
            }
            float* o = outs[f >> 2];
            int cg = (f & 3) * 16 + col;
#pragma unroll
            for (int r = 0; r < 4; r++)
                o[(row0w + g * 4 + r) * 64 + cg] = acc[r];
        }
    }
}

// ---------------------------------------------------------------------------
// K3: MFMA vector-attention (unchanged from R6). 1024 x 512; 1 query/wave.
// ---------------------------------------------------------------------------
__global__ __launch_bounds__(512, 4) void attn_kernel(
    const int4* __restrict__ idx4, const int* __restrict__ knn,
    const float* __restrict__ xq, const float* __restrict__ xk,
    const float* __restrict__ xv,
    const float* __restrict__ Wp1, const float* __restrict__ pg,
    const float* __restrict__ pb, const float* __restrict__ Wp2,
    const float* __restrict__ bp2,
    const float* __restrict__ wg1, const float* __restrict__ wb1,
    const float* __restrict__ Ww1,
    const float* __restrict__ wg2, const float* __restrict__ wb2,
    const float* __restrict__ Ww2, const float* __restrict__ bw2,
    float* __restrict__ attn)
{
    __shared__ _Float16 sW1t[128 * 72];
    __shared__ _Float16 sW2t[64 * 136];
    __shared__ _Float16 sscr[8][16 * 136];
    __shared__ float sWp1[48], sPg[16], sPb[16];

    const int t = threadIdx.x;
    const int lane = t & 63;
    const int wv = t >> 6;
    const int col = lane & 15, g = lane >> 4;
    const int q = blockIdx.x * 8 + wv;

    const int jA = knn[q * 16 + col];
    const int4 jC = *(const int4*)(knn + q * 16 + g * 4);
    const int jr[4] = {jC.x, jC.y, jC.z, jC.w};
    const int4 pc = idx4[jA];
    const int4 qc = idx4[q];
    float xqv[4], xkv[4][4], xvv[4][4];
#pragma unroll
    for (int f = 0; f < 4; f++) xqv[f] = xq[q * 64 + f * 16 + col];
#pragma unroll
    for (int r = 0; r < 4; r++)
#pragma unroll
        for (int f = 0; f < 4; f++) {
            xkv[r][f] = xk[jr[r] * 64 + f * 16 + col];
            xvv[r][f] = xv[jr[r] * 64 + f * 16 + col];
        }

    for (int e = t; e < 8192; e += 512) {
        int c = e >> 7, o = e & 127;
        sW1t[o * 72 + c] = (_Float16)Ww1[e];
    }
    for (int e = t; e < 8192; e += 512) {
        int n = e >> 6, m = e & 63;
        sW2t[m * 136 + n] = (_Float16)Ww2[e];
    }
    if (t < 48) sWp1[t] = Wp1[t];
    if (t < 16) { sPg[t] = pg[t] * BN_INV; sPb[t] = pb[t]; }

    float g1c[4], b1c[4], bp2c[4], bw2c[4], g2c[8], b2c[8];
#pragma unroll
    for (int f = 0; f < 4; f++) {
        int c = f * 16 + col;
        g1c[f] = wg1[c] * BN_INV; b1c[f] = wb1[c];
        bp2c[f] = bp2[c]; bw2c[f] = bw2[c];
    }
#pragma unroll
    for (int f = 0; f < 8; f++) {
        int o = f * 16 + col;
        g2c[f] = wg2[o] * BN_INV; b2c[f] = wb2[o];
    }
    f16x8 bP[4];
#pragma unroll
    for (int f = 0; f < 4; f++) {
#pragma unroll
        for (int j = 0; j < 8; j++) {
            int h = g * 8 + j;
            bP[f][j] = (g < 2) ? (_Float16)Wp2[h * 64 + f * 16 + col]
                               : (_Float16)0.f;
        }
    }
    __syncthreads();

    _Float16* scr = sscr[wv];

    const float px = (float)(pc.y - qc.y);
    const float py = (float)(pc.z - qc.z);
    const float pz = (float)(pc.w - qc.w);
    f16x8 aph;
#pragma unroll
    for (int j = 0; j < 8; j++) {
        int h = g * 8 + j;
        float v = 0.f;
        if (g < 2) {
            v = px * sWp1[h] + py * sWp1[16 + h] + pz * sWp1[32 + h];
            v = fmaxf(v * sPg[h] + sPb[h], 0.f);
        }
        aph[j] = (_Float16)v;
    }
    f32x4 pr[4];
#pragma unroll
    for (int f = 0; f < 4; f++) {
        f32x4 cini;
#pragma unroll
        for (int r = 0; r < 4; r++) cini[r] = bp2c[f];
        pr[f] = __builtin_amdgcn_mfma_f32_16x16x32_f16(aph, bP[f], cini,
                                                       0, 0, 0);
    }
    f32x4 vvr[4];
#pragma unroll
    for (int r = 0; r < 4; r++) {
#pragma unroll
        for (int f = 0; f < 4; f++) {
            float w0 = xkv[r][f] - xqv[f] + pr[f][r];
            float uu = fmaxf(w0 * g1c[f] + b1c[f], 0.f);
            scr[(g * 4 + r) * 72 + f * 16 + col] = (_Float16)uu;
            vvr[f][r] = xvv[r][f] + pr[f][r];
        }
    }
    f16x8 au[2];
#pragma unroll
    for (int kc = 0; kc < 2; kc++)
        au[kc] = *(const f16x8*)&scr[col * 72 + kc * 32 + g * 8];
    f32x4 acc1[8];
#pragma unroll
    for (int f = 0; f < 8; f++)
#pragma unroll
        for (int r = 0; r < 4; r++) acc1[f][r] = 0.f;
#pragma unroll
    for (int kc = 0; kc < 2; kc++) {
#pragma unroll
        for (int f = 0; f < 8; f++) {
            f16x8 bw = *(const f16x8*)
                &sW1t[(f * 16 + col) * 72 + kc * 32 + g * 8];
            acc1[f] = __builtin_amdgcn_mfma_f32_16x16x32_f16(au[kc], bw,
                                                             acc1[f], 0, 0, 0);
        }
    }
#pragma unroll
    for (int f = 0; f < 8; f++)
#pragma unroll
        for (int r = 0; r < 4; r++) {
            float o1 = fmaxf(acc1[f][r] * g2c[f] + b2c[f], 0.f);
            scr[(g * 4 + r) * 136 + f * 16 + col] = (_Float16)o1;
        }
    f16x8 ao[4];
#pragma unroll
    for (int kc = 0; kc < 4; kc++)
        ao[kc] = *(const f16x8*)&scr[col * 136 + kc * 32 + g * 8];
    f32x4 accL[4];
#pragma unroll
    for (int f = 0; f < 4; f++)
#pragma unroll
        for (int r = 0; r < 4; r++) accL[f][r] = bw2c[f];
#pragma unroll
    for (int kc = 0; kc < 4; kc++) {
#pragma unroll
        for (int f = 0; f < 4; f++) {
            f16x8 bw = *(const f16x8*)
                &sW2t[(f * 16 + col) * 136 + kc * 32 + g * 8];
            accL[f] = __builtin_amdgcn_mfma_f32_16x16x32_f16(ao[kc], bw,
                                                             accL[f], 0, 0, 0);
        }
    }
    float outv[4];
#pragma unroll
    for (int f = 0; f < 4; f++) {
        float mx = fmaxf(fmaxf(accL[f][0], accL[f][1]),
                         fmaxf(accL[f][2], accL[f][3]));
        mx = fmaxf(mx, __shfl_xor(mx, 16, 64));
        mx = fmaxf(mx, __shfl_xor(mx, 32, 64));
        float sum = 0.f, part = 0.f;
#pragma unroll
        for (int r = 0; r < 4; r++) {
            float e = __expf(accL[f][r] - mx);
            sum += e;
            part = fmaf(e, vvr[f][r], part);
        }
        sum += __shfl_xor(sum, 16, 64);
        sum += __shfl_xor(sum, 32, 64);
        part += __shfl_xor(part, 16, 64);
        part += __shfl_xor(part, 32, 64);
        outv[f] = part / sum;
    }
    float val = (g == 0) ? outv[0]
              : (g == 1) ? outv[1]
              : (g == 2) ? outv[2] : outv[3];
    attn[q * 64 + lane] = val;
}

// ---------------------------------------------------------------------------
// K4: FUSED MFMA-f16 head: out = LN(relu(bn(relu(bn([feats,attn]@Wc1))@Wc2))
//                                     @Wc3 + bc3)
// 256 blocks x 256 thr; 32 rows/block; wave (rg,hf): rows rg*16.., col half
// hf. Weights restaged into one 35KB B-frag slab per layer; h tiles as f16
// A-frags in LDS; f32 LN epilogue via width-8 shuffle.
// ---------------------------------------------------------------------------
__global__ __launch_bounds__(256) void head_kernel(
    const float* __restrict__ feats, const float* __restrict__ attn,
    const float* __restrict__ Wc1, const float* __restrict__ cg1,
    const float* __restrict__ cb1, const float* __restrict__ Wc2,
    const float* __restrict__ cg2, const float* __restrict__ cb2,
    const float* __restrict__ Wc3, const float* __restrict__ bc3,
    const float* __restrict__ lng, const float* __restrict__ lnb,
    float* __restrict__ out)
{
    __shared__ _Float16 sWt[128 * 136]; // 34.8KB, reused per layer
    __shared__ _Float16 sX[2][16 * 136];
    __shared__ _Float16 sY[2][16 * 136];
    __shared__ float sOut[32 * 68];
    __shared__ float sga[128], sba[128], sgb[128], sbb[128];
    __shared__ float sbc3[64], slng[64], slnb[64];

    const int t = threadIdx.x;
    const int lane = t & 63;
    const int wv = t >> 6;
    const int rg = wv >> 1, hf = wv & 1;
    const int col = lane & 15, g = lane >> 4;
    const int row0 = blockIdx.x * 32;

    // stage input rows as f16 A-frags
    {
        int r = t >> 3, c0 = (t & 7) * 16;
        const float* src = (c0 < 64) ? (feats + (row0 + r) * 64 + c0)
                                     : (attn + (row0 + r) * 64 + (c0 - 64));
        _Float16* dst = &sX[r >> 4][(r & 15) * 136 + c0];
#pragma unroll
        for (int i = 0; i < 4; i++) {
            float4 v = ((const float4*)src)[i];
            dst[i * 4 + 0] = (_Float16)v.x;
            dst[i * 4 + 1] = (_Float16)v.y;
            dst[i * 4 + 2] = (_Float16)v.z;
            dst[i * 4 + 3] = (_Float16)v.w;
        }
    }
    // stage W1 transposed, params
    auto stageW128 = [&](const float* W) {
        int c = t >> 1, ob = (t & 1) * 64;
        const float4* src = (const float4*)(W + c * 128 + ob);
#pragma unroll
        for (int i = 0; i < 16; i++) {
            float4 w = src[i];
            _Float16* d = &sWt[(ob + i * 4) * 136 + c];
            d[0 * 136] = (_Float16)w.x; d[1 * 136] = (_Float16)w.y;
            d[2 * 136] = (_Float16)w.z; d[3 * 136] = (_Float16)w.w;
        }
    };
    stageW128(Wc1);
    if (t < 128) {
        sga[t] = cg1[t] * BN_INV; sba[t] = cb1[t];
        sgb[t] = cg2[t] * BN_INV; sbb[t] = cb2[t];
    } else if (t < 192) {
        int o = t - 128;
        sbc3[o] = bc3[o]; slng[o] = lng[o]; slnb[o] = lnb[o];
    }
    __syncthreads();
    // layer 1: sX @ W1 -> bn+relu -> sY
    {
        f16x8 ax[4];
#pragma unroll
        for (int kc = 0; kc < 4; kc++)
            ax[kc] = *(const f16x8*)&sX[rg][col * 136 + kc * 32 + g * 8];
        f32x4 acc[4];
#pragma unroll
        for (int ft = 0; ft < 4; ft++)
#pragma unroll
            for (int r = 0; r < 4; r++) acc[ft][r] = 0.f;
#pragma unroll
        for (int kc = 0; kc < 4; kc++)
#pragma unroll
            for (int ft = 0; ft < 4; ft++) {
                int n = hf * 64 + ft * 16 + col;
                f16x8 bw = *(const f16x8*)&sWt[n * 136 + kc * 32 + g * 8];
                acc[ft] = __builtin_amdgcn_mfma_f32_16x16x32_f16(ax[kc], bw,
                                                                 acc[ft],
                                                                 0, 0, 0);
            }
#pragma unroll
        for (int ft = 0; ft < 4; ft++)
#pragma unroll
            for (int r = 0; r < 4; r++) {
                int o = hf * 64 + ft * 16 + col;
                float v = fmaxf(acc[ft][r] * sga[o] + sba[o], 0.f);
                sY[rg][(g * 4 + r) * 136 + o] = (_Float16)v;
            }
    }
    __syncthreads();
    stageW128(Wc2);
    __syncthreads();
    // layer 2: sY @ W2 -> bn+relu -> sX
    {
        f16x8 ax[4];
#pragma unroll
        for (int kc = 0; kc < 4; kc++)
            ax[kc] = *(const f16x8*)&sY[rg][col * 136 + kc * 32 + g * 8];
        f32x4 acc[4];
#pragma unroll
        for (int ft = 0; ft < 4; ft++)
#pragma unroll
            for (int r = 0; r < 4; r++) acc[ft][r] = 0.f;
#pragma unroll
        for (int kc = 0; kc < 4; kc++)
#pragma unroll
            for (int ft = 0; ft < 4; ft++) {
                int n = hf * 64 + ft * 16 + col;
                f16x8 bw = *(const f16x8*)&sWt[n * 136 + kc * 32 + g * 8];
                acc[ft] = __builtin_amdgcn_mfma_f32_16x16x32_f16(ax[kc], bw,
                                                                 acc[ft],
                                                                 0, 0, 0);
            }
#pragma unroll
        for (int ft = 0; ft < 4; ft++)
#pragma unroll
            for (int r = 0; r < 4; r++) {
                int o = hf * 64 + ft * 16 + col;
                float v = fmaxf(acc[ft][r] * sgb[o] + sbb[o], 0.f);
                sX[rg][(g * 4 + r) * 136 + o] = (_Float16)v;
            }
    }
    __syncthreads();
    // stage W3 (128x64)
    {
        int c = t >> 1, ob = (t & 1) * 32;
        const float4* src = (const float4*)(Wc3 + c * 64 + ob);
#pragma unroll
        for (int i = 0; i < 8; i++) {
            float4 w = src[i];
            _Float16* d = &sWt[(ob + i * 4) * 136 + c];
            d[0 * 136] = (_Float16)w.x; d[1 * 136] = (_Float16)w.y;
            d[2 * 136] = (_Float16)w.z; d[3 * 136] = (_Float16)w.w;
        }
    }
    __syncthreads();
    // layer 3: sX @ W3 + bc3 -> sOut (f32)
    {
        f16x8 ax[4];
#pragma unroll
        for (int kc = 0; kc < 4; kc++)
            ax[kc] = *(const f16x8*)&sX[rg][col * 136 + kc * 32 + g * 8];
#pragma unroll
        for (int ft = 0; ft < 2; ft++) {
            int n = hf * 32 + ft * 16 + col;
            f32x4 acc;
            float bias = sbc3[n];
#pragma unroll
            for (int r = 0; r < 4; r++) acc[r] = bias;
#pragma unroll
            for (int kc = 0; kc < 4; kc++) {
                f16x8 bw = *(const f16x8*)&sWt[n * 136 + kc * 32 + g * 8];
                acc = __builtin_amdgcn_mfma_f32_16x16x32_f16(ax[kc], bw, acc,
                                                             0, 0, 0);
            }
#pragma unroll
            for (int r = 0; r < 4; r++)
                sOut[(rg * 16 + g * 4 + r) * 68 + n] = acc[r];
        }
    }
    __syncthreads();
    // LayerNorm epilogue (f32), width-8 shuffle reduce
    {
        int r = t >> 3, o0 = (t & 7) * 8;
        float v[8];
        float s1 = 0.f, s2 = 0.f;
#pragma unroll
        for (int k = 0; k < 8; k++) {
            v[k] = sOut[r * 68 + o0 + k];
            s1 += v[k];
            s2 = fmaf(v[k], v[k], s2);
        }
#pragma unroll
        for (int d = 1; d < 8; d <<= 1) {
            s1 += __shfl_xor(s1, d, 8);
            s2 += __shfl_xor(s2, d, 8);
        }
        float m = s1 * (1.f / 64.f);
        float var = s2 * (1.f / 64.f) - m * m;
        float inv = 1.f / sqrtf(var + LN_EPS);
        float* dst = out + (row0 + r) * 64;
#pragma unroll
        for (int k = 0; k < 8; k++) {
            int o = o0 + k;
            dst[o] = (v[k] - m) * inv * slng[o] + slnb[o];
        }
    }
}

// ---------------------------------------------------------------------------
extern "C" void kernel_launch(void* const* d_in, const int* in_sizes, int n_in,
                              void* d_out, int out_size, void* d_ws,
                              size_t ws_size, hipStream_t stream)
{
    const int* indices = (const int*)d_in[0];
    const float* feats = (const float*)d_in[1];
    const float* Wq = (const float*)d_in[2];
    const float* bq = (const float*)d_in[3];
    const float* Wk = (const float*)d_in[4];
    const float* bk = (const float*)d_in[5];
    const float* Wv = (const float*)d_in[6];
    const float* bv = (const float*)d_in[7];
    const float* Wp1 = (const float*)d_in[8];
    const float* pg = (const float*)d_in[9];
    const float* pb = (const float*)d_in[10];
    const float* Wp2 = (const float*)d_in[11];
    const float* bp2 = (const float*)d_in[12];
    const float* wg1 = (const float*)d_in[13];
    const float* wb1 = (const float*)d_in[14];
    const float* Ww1 = (const float*)d_in[15];
    const float* wg2 = (const float*)d_in[16];
    const float* wb2 = (const float*)d_in[17];
    const float* Ww2 = (const float*)d_in[18];
    const float* bw2 = (const float*)d_in[19];
    const float* Wc1 = (const float*)d_in[20];
    const float* cg1 = (const float*)d_in[21];
    const float* cb1 = (const float*)d_in[22];
    const float* Wc2 = (const float*)d_in[23];
    const float* cg2 = (const float*)d_in[24];
    const float* cb2 = (const float*)d_in[25];
    const float* Wc3 = (const float*)d_in[26];
    const float* bc3 = (const float*)d_in[27];
    const float* lng = (const float*)d_in[28];
    const float* lnb = (const float*)d_in[29];

    float* out = (float*)d_out;
    float* ws = (float*)d_ws;
    float* xq = ws;
    float* xk = xq + N * C;
    float* xv = xk + N * C;
    float* attn = xv + N * C;
    int* knn = (int*)(attn + N * C);

    qkv_knn_kernel<<<1088, 512, 32768, stream>>>(
        (const int4*)indices, knn, feats, Wq, bq, Wk, bk, Wv, bv, xq, xk, xv);
    attn_kernel<<<1024, 512, 0, stream>>>((const int4*)indices, knn, xq, xk,
                                          xv, Wp1, pg, pb, Wp2, bp2, wg1, wb1,
                                          Ww1, wg2, wb2, Ww2, bw2, attn);
    head_kernel<<<256, 256, 0, stream>>>(feats, attn, Wc1, cg1, cb1, Wc2, cg2,
                                         cb2, Wc3, bc3, lng, lnb, out);
}